// Round 1
// baseline (692.619 us; speedup 1.0000x reference)
//
#include <hip/hip_runtime.h>
#include <hip/hip_bf16.h>

#define NN 20000
#define NE 320000
#define NG 16
#define HID 128

// ---------------- CSR build ----------------

__global__ void hist_kernel(const int* __restrict__ dst, int* __restrict__ indeg, int E) {
  int e = blockIdx.x * 256 + threadIdx.x;
  if (e < E) atomicAdd(&indeg[dst[e]], 1);
}

__global__ void exscan_kernel(const int* __restrict__ in, int* __restrict__ outp, int n) {
  __shared__ int buf[1024];
  __shared__ int carry_s;
  int t = threadIdx.x;
  if (t == 0) carry_s = 0;
  __syncthreads();
  for (int base = 0; base < n; base += 1024) {
    int i = base + t;
    int v = (i < n) ? in[i] : 0;
    buf[t] = v;
    __syncthreads();
    int x = v;
    for (int off = 1; off < 1024; off <<= 1) {
      int y = (t >= off) ? buf[t - off] : 0;
      __syncthreads();
      x += y;
      buf[t] = x;
      __syncthreads();
    }
    int carry = carry_s;
    if (i < n) outp[i] = carry + x - v;   // exclusive prefix
    __syncthreads();
    if (t == 1023) carry_s = carry + x;
    __syncthreads();
  }
  if (t == 0) outp[n] = carry_s;
}

__global__ void scatter_kernel(const int* __restrict__ src, const int* __restrict__ dst,
                               const int* __restrict__ rowptr, int* __restrict__ cursor,
                               int* __restrict__ csr_src, int E) {
  int e = blockIdx.x * 256 + threadIdx.x;
  if (e < E) {
    int d = dst[e];
    int p = atomicAdd(&cursor[d], 1);
    csr_src[rowptr[d] + p] = src[e];
  }
}

// ---------------- GEMM: C[M,NFULL] = A[M,K] @ B[K,NFULL] ----------------
// tile: 16 rows x 128 cols; 256 threads; thread = 4 rows x 2 cols

template <int K, int NFULL>
__global__ void gemm16_kernel(const float* __restrict__ A, const float* __restrict__ B,
                              float* __restrict__ C, int M) {
  __shared__ float As[K * 16];  // transposed: As[k*16 + r]
  int row0 = blockIdx.x * 16;
  int col0 = blockIdx.y * 128;
  int tid = threadIdx.x;
  for (int idx = tid; idx < 16 * K; idx += 256) {
    int r = idx / K, k = idx - r * K;
    int row = row0 + r;
    As[k * 16 + r] = (row < M) ? A[(size_t)row * K + k] : 0.f;
  }
  __syncthreads();
  int c2 = tid & 63;
  int rg = tid >> 6;
  int c = col0 + c2 * 2;
  float acc00 = 0.f, acc01 = 0.f, acc10 = 0.f, acc11 = 0.f;
  float acc20 = 0.f, acc21 = 0.f, acc30 = 0.f, acc31 = 0.f;
#pragma unroll 8
  for (int k = 0; k < K; k++) {
    float4 a = *(const float4*)&As[k * 16 + rg * 4];
    float2 b = *(const float2*)&B[(size_t)k * NFULL + c];
    acc00 += a.x * b.x; acc01 += a.x * b.y;
    acc10 += a.y * b.x; acc11 += a.y * b.y;
    acc20 += a.z * b.x; acc21 += a.z * b.y;
    acc30 += a.w * b.x; acc31 += a.w * b.y;
  }
  float accs[4][2] = {{acc00, acc01}, {acc10, acc11}, {acc20, acc21}, {acc30, acc31}};
  for (int j = 0; j < 4; j++) {
    int row = row0 + rg * 4 + j;
    if (row < M) *(float2*)&C[(size_t)row * NFULL + c] = make_float2(accs[j][0], accs[j][1]);
  }
}

// ---------------- attention coefficients: el/er per (node, head) ----------------
// one wave per (n,h); feature dim 128 = 2 elems/lane

__global__ void att_coef_kernel(const float* __restrict__ f, const float* __restrict__ al,
                                const float* __restrict__ ar, float* __restrict__ el,
                                float* __restrict__ er, int NH, int H) {
  int w = (blockIdx.x * 256 + threadIdx.x) >> 6;
  int lane = threadIdx.x & 63;
  if (w >= NH) return;
  int h = w % H;
  const float* fr = f + (size_t)w * 128;  // f layout [n, H, 128]; w = n*H+h
  float v0 = fr[lane], v1 = fr[64 + lane];
  float a0 = al[h * 128 + lane], a1 = al[h * 128 + 64 + lane];
  float r0 = ar[h * 128 + lane], r1 = ar[h * 128 + 64 + lane];
  float se = v0 * a0 + v1 * a1;
  float sr = v0 * r0 + v1 * r1;
  for (int off = 32; off; off >>= 1) {
    se += __shfl_down(se, off);
    sr += __shfl_down(sr, off);
  }
  if (lane == 0) { el[w] = se; er[w] = sr; }
}

// ---------------- per-dst-node softmax aggregation ----------------
// block = 128 threads (feature dim d), one block per node
// e = leaky_relu(el[src] + er[dst]); w = exp(e) (no max-sub: |e| <~ 8, safe)
// out[n,h,d] = (sum_e w*f[src,h,d]) / (sum_e w)  + bias, optional ELU

template <int H, bool ELU>
__global__ void aggregate_kernel(const float* __restrict__ f, const float* __restrict__ el,
                                 const float* __restrict__ er, const float* __restrict__ bias,
                                 const int* __restrict__ rowptr, const int* __restrict__ csr_src,
                                 float* __restrict__ out) {
  int n = blockIdx.x;
  int tid = threadIdx.x;  // 128
  __shared__ float wbuf[H][128];
  __shared__ int sbuf[128];
  __shared__ float red[2 * H];
  int rs = rowptr[n];
  int deg = rowptr[n + 1] - rs;
  float erh[H];
#pragma unroll
  for (int h = 0; h < H; h++) erh[h] = er[n * H + h];
  float psum[H];
  float acc[H];
#pragma unroll
  for (int h = 0; h < H; h++) { psum[h] = 0.f; acc[h] = 0.f; }
  int d = tid;
  for (int base = 0; base < deg; base += 128) {
    int cnt = min(128, deg - base);
    if (tid < cnt) {
      int s = csr_src[rs + base + tid];
      sbuf[tid] = s;
#pragma unroll
      for (int h = 0; h < H; h++) {
        float e = el[s * H + h] + erh[h];
        e = e > 0.f ? e : 0.2f * e;
        float w = __expf(e);
        wbuf[h][tid] = w;
        psum[h] += w;
      }
    }
    __syncthreads();
    for (int j = 0; j < cnt; j++) {
      int s = sbuf[j];
      const float* fr = f + (size_t)s * (H * 128);
#pragma unroll
      for (int h = 0; h < H; h++) acc[h] += wbuf[h][j] * fr[h * 128 + d];
    }
    __syncthreads();
  }
  // reduce psum across the 2 waves
#pragma unroll
  for (int h = 0; h < H; h++)
    for (int off = 32; off; off >>= 1) psum[h] += __shfl_down(psum[h], off);
  int wv = tid >> 6, ln = tid & 63;
  if (ln == 0) {
#pragma unroll
    for (int h = 0; h < H; h++) red[wv * H + h] = psum[h];
  }
  __syncthreads();
#pragma unroll
  for (int h = 0; h < H; h++) {
    float denom = red[h] + red[H + h];
    float r = (denom > 0.f ? acc[h] / denom : 0.f) + bias[h * 128 + d];
    if (ELU) r = r > 0.f ? r : expm1f(r);
    out[(size_t)n * (H * 128) + h * 128 + d] = r;
  }
}

// ---------------- mean-pool per graph (+ fused linear head + relu) ----------------
// graph_ids is sorted ascending -> binary search for segment boundaries

__global__ void pool_final_kernel(const float* __restrict__ h2, const int* __restrict__ gid,
                                  const float* __restrict__ linW, const float* __restrict__ linb,
                                  float* __restrict__ out, int N) {
  int g = blockIdx.x;
  int tid = threadIdx.x;  // 128
  // lower_bound(g) and lower_bound(g+1)
  int lo0 = 0, hi0 = N;
  while (lo0 < hi0) { int m = (lo0 + hi0) >> 1; if (gid[m] < g) lo0 = m + 1; else hi0 = m; }
  int lo1 = lo0, hi1 = N;
  while (lo1 < hi1) { int m = (lo1 + hi1) >> 1; if (gid[m] < g + 1) lo1 = m + 1; else hi1 = m; }
  float acc = 0.f;
  for (int n = lo0; n < lo1; n++) acc += h2[(size_t)n * 128 + tid];
  int cnt = lo1 - lo0;
  float hg = acc / (float)(cnt > 0 ? cnt : 1);
  __shared__ float hgs[128];
  hgs[tid] = hg;
  __syncthreads();
  float o = linb[tid];
  for (int dd = 0; dd < 128; dd++) o += hgs[dd] * linW[dd * 128 + tid];
  out[g * 128 + tid] = fmaxf(o, 0.f);
}

// ---------------- launch ----------------

extern "C" void kernel_launch(void* const* d_in, const int* in_sizes, int n_in,
                              void* d_out, int out_size, void* d_ws, size_t ws_size,
                              hipStream_t stream) {
  const float* x    = (const float*)d_in[0];   // [20000,128]
  const int*   src  = (const int*)d_in[1];     // [320000]
  const int*   dst  = (const int*)d_in[2];     // [320000]
  const int*   gid  = (const int*)d_in[3];     // [20000] sorted
  const float* W1   = (const float*)d_in[4];   // [128,384]
  const float* al1  = (const float*)d_in[5];   // [3,128]
  const float* ar1  = (const float*)d_in[6];   // [3,128]
  const float* b1   = (const float*)d_in[7];   // [384]
  const float* W2   = (const float*)d_in[8];   // [384,128]
  const float* al2  = (const float*)d_in[9];   // [1,128]
  const float* ar2  = (const float*)d_in[10];  // [1,128]
  const float* b2   = (const float*)d_in[11];  // [128]
  const float* linW = (const float*)d_in[12];  // [128,128]
  const float* linb = (const float*)d_in[13];  // [128]
  float* out = (float*)d_out;                  // [16,128]

  char* ws = (char*)d_ws;
  size_t off = 0;
  auto alloc = [&](size_t bytes) -> void* {
    void* p = ws + off;
    off += (bytes + 255) & ~(size_t)255;
    return p;
  };
  float* f1      = (float*)alloc((size_t)NN * 384 * 4);  // 30.72 MB
  float* h1      = (float*)alloc((size_t)NN * 384 * 4);  // 30.72 MB
  float* f2      = (float*)alloc((size_t)NN * 128 * 4);  // 10.24 MB
  float* h2      = (float*)alloc((size_t)NN * 128 * 4);  // 10.24 MB
  float* el1     = (float*)alloc((size_t)NN * 3 * 4);
  float* er1     = (float*)alloc((size_t)NN * 3 * 4);
  float* el2     = (float*)alloc((size_t)NN * 4);
  float* er2     = (float*)alloc((size_t)NN * 4);
  int*   indeg   = (int*)alloc((size_t)NN * 4);
  int*   rowptr  = (int*)alloc((size_t)(NN + 1) * 4);
  int*   cursor  = (int*)alloc((size_t)NN * 4);
  int*   csr_src = (int*)alloc((size_t)NE * 4);
  (void)ws_size;

  // CSR build (structural; shared by both GAT layers)
  hipMemsetAsync(indeg, 0, (size_t)NN * 4, stream);
  hipMemsetAsync(cursor, 0, (size_t)NN * 4, stream);
  hist_kernel<<<(NE + 255) / 256, 256, 0, stream>>>(dst, indeg, NE);
  exscan_kernel<<<1, 1024, 0, stream>>>(indeg, rowptr, NN);
  scatter_kernel<<<(NE + 255) / 256, 256, 0, stream>>>(src, dst, rowptr, cursor, csr_src, NE);

  // Layer 1: f1 = x @ W1 ; el1/er1 ; aggregate(+b1, ELU) -> h1
  gemm16_kernel<128, 384><<<dim3(1250, 3), 256, 0, stream>>>(x, W1, f1, NN);
  att_coef_kernel<<<(NN * 3 + 3) / 4, 256, 0, stream>>>(f1, al1, ar1, el1, er1, NN * 3, 3);
  aggregate_kernel<3, true><<<NN, 128, 0, stream>>>(f1, el1, er1, b1, rowptr, csr_src, h1);

  // Layer 2: f2 = h1 @ W2 ; el2/er2 ; aggregate(+b2) -> h2
  gemm16_kernel<384, 128><<<dim3(1250, 1), 256, 0, stream>>>(h1, W2, f2, NN);
  att_coef_kernel<<<(NN + 3) / 4, 256, 0, stream>>>(f2, al2, ar2, el2, er2, NN, 1);
  aggregate_kernel<1, false><<<NN, 128, 0, stream>>>(f2, el2, er2, b2, rowptr, csr_src, h2);

  // Mean-pool per graph + linear head + relu
  pool_final_kernel<<<NG, 128, 0, stream>>>(h2, gid, linW, linb, out, NN);
}

// Round 2
// 393.931 us; speedup vs baseline: 1.7582x; 1.7582x over previous
//
#include <hip/hip_runtime.h>
#include <hip/hip_bf16.h>

#define NN 20000
#define NE 320000
#define NG 16
#define HID 128
#define PSPLIT 32

// ---------------- CSR build ----------------

__global__ void hist_kernel(const int* __restrict__ dst, int* __restrict__ indeg, int E) {
  int e = blockIdx.x * 256 + threadIdx.x;
  if (e < E) atomicAdd(&indeg[dst[e]], 1);
}

// single-block exclusive scan, shfl-based (2 barriers per 1024-chunk)
__global__ void exscan_kernel(const int* __restrict__ in, int* __restrict__ outp, int n) {
  __shared__ int wsum[16];
  __shared__ int wexcl[16];
  __shared__ int tot_s;
  __shared__ int carry_s;
  int t = threadIdx.x;
  int lane = t & 63, wv = t >> 6;
  if (t == 0) carry_s = 0;
  __syncthreads();
  for (int base = 0; base < n; base += 1024) {
    int i = base + t;
    int v = (i < n) ? in[i] : 0;
    int x = v;
#pragma unroll
    for (int off = 1; off < 64; off <<= 1) {
      int y = __shfl_up(x, off);
      if (lane >= off) x += y;
    }
    if (lane == 63) wsum[wv] = x;
    __syncthreads();  // B1
    int carry = carry_s;
    if (t < 16) {
      int s = wsum[t];
      int xs = s;
#pragma unroll
      for (int off = 1; off < 16; off <<= 1) {
        int y = __shfl_up(xs, off);
        if (t >= off) xs += y;
      }
      wexcl[t] = xs - s;
      if (t == 15) tot_s = xs;
    }
    __syncthreads();  // B2
    if (i < n) outp[i] = carry + wexcl[wv] + (x - v);
    if (t == 0) carry_s = carry + tot_s;
  }
  if (t == 0) outp[n] = carry_s;
}

__global__ void scatter_kernel(const int* __restrict__ src, const int* __restrict__ dst,
                               const int* __restrict__ rowptr, int* __restrict__ cursor,
                               int* __restrict__ csr_src, int E) {
  int e = blockIdx.x * 256 + threadIdx.x;
  if (e < E) {
    int d = dst[e];
    int p = atomicAdd(&cursor[d], 1);
    csr_src[rowptr[d] + p] = src[e];
  }
}

// ---------------- GEMM: C[M,NFULL] = A[M,K] @ B[K,NFULL] ----------------

template <int K, int NFULL>
__global__ void gemm16_kernel(const float* __restrict__ A, const float* __restrict__ B,
                              float* __restrict__ C, int M) {
  __shared__ float As[K * 16];  // transposed: As[k*16 + r]
  int row0 = blockIdx.x * 16;
  int col0 = blockIdx.y * 128;
  int tid = threadIdx.x;
  for (int idx = tid; idx < 16 * K; idx += 256) {
    int r = idx / K, k = idx - r * K;
    int row = row0 + r;
    As[k * 16 + r] = (row < M) ? A[(size_t)row * K + k] : 0.f;
  }
  __syncthreads();
  int c2 = tid & 63;
  int rg = tid >> 6;
  int c = col0 + c2 * 2;
  float acc00 = 0.f, acc01 = 0.f, acc10 = 0.f, acc11 = 0.f;
  float acc20 = 0.f, acc21 = 0.f, acc30 = 0.f, acc31 = 0.f;
#pragma unroll 8
  for (int k = 0; k < K; k++) {
    float4 a = *(const float4*)&As[k * 16 + rg * 4];
    float2 b = *(const float2*)&B[(size_t)k * NFULL + c];
    acc00 += a.x * b.x; acc01 += a.x * b.y;
    acc10 += a.y * b.x; acc11 += a.y * b.y;
    acc20 += a.z * b.x; acc21 += a.z * b.y;
    acc30 += a.w * b.x; acc31 += a.w * b.y;
  }
  float accs[4][2] = {{acc00, acc01}, {acc10, acc11}, {acc20, acc21}, {acc30, acc31}};
  for (int j = 0; j < 4; j++) {
    int row = row0 + rg * 4 + j;
    if (row < M) *(float2*)&C[(size_t)row * NFULL + c] = make_float2(accs[j][0], accs[j][1]);
  }
}

// ---------------- attention coefficients ----------------

__global__ void att_coef_kernel(const float* __restrict__ f, const float* __restrict__ al,
                                const float* __restrict__ ar, float* __restrict__ el,
                                float* __restrict__ er, int NH, int H) {
  int w = (blockIdx.x * 256 + threadIdx.x) >> 6;
  int lane = threadIdx.x & 63;
  if (w >= NH) return;
  int h = w % H;
  const float* fr = f + (size_t)w * 128;
  float v0 = fr[lane], v1 = fr[64 + lane];
  float a0 = al[h * 128 + lane], a1 = al[h * 128 + 64 + lane];
  float r0 = ar[h * 128 + lane], r1 = ar[h * 128 + 64 + lane];
  float se = v0 * a0 + v1 * a1;
  float sr = v0 * r0 + v1 * r1;
  for (int off = 32; off; off >>= 1) {
    se += __shfl_down(se, off);
    sr += __shfl_down(sr, off);
  }
  if (lane == 0) { el[w] = se; er[w] = sr; }
}

// ---------------- per-dst-node softmax aggregation ----------------
// edge loop manually unrolled x4: 4*H independent gather loads in flight

template <int H, bool ELU>
__global__ void aggregate_kernel(const float* __restrict__ f, const float* __restrict__ el,
                                 const float* __restrict__ er, const float* __restrict__ bias,
                                 const int* __restrict__ rowptr, const int* __restrict__ csr_src,
                                 float* __restrict__ out) {
  int n = blockIdx.x;
  int tid = threadIdx.x;  // 128
  __shared__ float wbuf[H][128];
  __shared__ int sbuf[128];
  __shared__ float red[2 * H];
  int rs = rowptr[n];
  int deg = rowptr[n + 1] - rs;
  float erh[H];
#pragma unroll
  for (int h = 0; h < H; h++) erh[h] = er[n * H + h];
  float psum[H];
  float acc[H];
#pragma unroll
  for (int h = 0; h < H; h++) { psum[h] = 0.f; acc[h] = 0.f; }
  int d = tid;
  for (int base = 0; base < deg; base += 128) {
    int cnt = min(128, deg - base);
    if (tid < cnt) {
      int s = csr_src[rs + base + tid];
      sbuf[tid] = s;
#pragma unroll
      for (int h = 0; h < H; h++) {
        float e = el[s * H + h] + erh[h];
        e = e > 0.f ? e : 0.2f * e;
        float w = __expf(e);
        wbuf[h][tid] = w;
        psum[h] += w;
      }
    }
    __syncthreads();
    int j = 0;
    for (; j + 4 <= cnt; j += 4) {
      int s0 = sbuf[j], s1 = sbuf[j + 1], s2 = sbuf[j + 2], s3 = sbuf[j + 3];
      const float* p0 = f + (size_t)s0 * (H * 128) + d;
      const float* p1 = f + (size_t)s1 * (H * 128) + d;
      const float* p2 = f + (size_t)s2 * (H * 128) + d;
      const float* p3 = f + (size_t)s3 * (H * 128) + d;
#pragma unroll
      for (int h = 0; h < H; h++) {
        float v0 = p0[h * 128], v1 = p1[h * 128], v2 = p2[h * 128], v3 = p3[h * 128];
        acc[h] += wbuf[h][j] * v0 + wbuf[h][j + 1] * v1 + wbuf[h][j + 2] * v2 + wbuf[h][j + 3] * v3;
      }
    }
    for (; j < cnt; j++) {
      int s = sbuf[j];
      const float* fr = f + (size_t)s * (H * 128) + d;
#pragma unroll
      for (int h = 0; h < H; h++) acc[h] += wbuf[h][j] * fr[h * 128];
    }
    __syncthreads();
  }
#pragma unroll
  for (int h = 0; h < H; h++)
    for (int off = 32; off; off >>= 1) psum[h] += __shfl_down(psum[h], off);
  int wv = tid >> 6, ln = tid & 63;
  if (ln == 0) {
#pragma unroll
    for (int h = 0; h < H; h++) red[wv * H + h] = psum[h];
  }
  __syncthreads();
#pragma unroll
  for (int h = 0; h < H; h++) {
    float denom = red[h] + red[H + h];
    float r = (denom > 0.f ? acc[h] / denom : 0.f) + bias[h * 128 + d];
    if (ELU) r = r > 0.f ? r : expm1f(r);
    out[(size_t)n * (H * 128) + h * 128 + d] = r;
  }
}

// ---------------- mean-pool: 2-stage ----------------
// stage 1: NG*PSPLIT blocks of 128 threads, partial sums + one atomicAdd per cell
__global__ void pool_partial_kernel(const float* __restrict__ h2, const int* __restrict__ gid,
                                    float* __restrict__ sums, int N) {
  int g = blockIdx.x / PSPLIT;
  int sp = blockIdx.x % PSPLIT;
  int tid = threadIdx.x;  // 128
  int lo0 = 0, hi0 = N;
  while (lo0 < hi0) { int m = (lo0 + hi0) >> 1; if (gid[m] < g) lo0 = m + 1; else hi0 = m; }
  int lo1 = lo0, hi1 = N;
  while (lo1 < hi1) { int m = (lo1 + hi1) >> 1; if (gid[m] < g + 1) lo1 = m + 1; else hi1 = m; }
  float a0 = 0.f, a1 = 0.f, a2 = 0.f, a3 = 0.f;
  int n = lo0 + sp;
  for (; n + 3 * PSPLIT < lo1; n += 4 * PSPLIT) {
    a0 += h2[(size_t)n * 128 + tid];
    a1 += h2[(size_t)(n + PSPLIT) * 128 + tid];
    a2 += h2[(size_t)(n + 2 * PSPLIT) * 128 + tid];
    a3 += h2[(size_t)(n + 3 * PSPLIT) * 128 + tid];
  }
  for (; n < lo1; n += PSPLIT) a0 += h2[(size_t)n * 128 + tid];
  float acc = (a0 + a1) + (a2 + a3);
  if (acc != 0.f || true) atomicAdd(&sums[g * 128 + tid], acc);
}

// stage 2: divide by count, 128x128 matvec, relu
__global__ void pool_final_kernel(const float* __restrict__ sums, const int* __restrict__ gid,
                                  const float* __restrict__ linW, const float* __restrict__ linb,
                                  float* __restrict__ out, int N) {
  int g = blockIdx.x;
  int tid = threadIdx.x;  // 128
  int lo0 = 0, hi0 = N;
  while (lo0 < hi0) { int m = (lo0 + hi0) >> 1; if (gid[m] < g) lo0 = m + 1; else hi0 = m; }
  int lo1 = lo0, hi1 = N;
  while (lo1 < hi1) { int m = (lo1 + hi1) >> 1; if (gid[m] < g + 1) lo1 = m + 1; else hi1 = m; }
  int cnt = lo1 - lo0;
  float hg = sums[g * 128 + tid] / (float)(cnt > 0 ? cnt : 1);
  __shared__ float hgs[128];
  hgs[tid] = hg;
  __syncthreads();
  float o = linb[tid];
#pragma unroll 4
  for (int dd = 0; dd < 128; dd++) o += hgs[dd] * linW[dd * 128 + tid];
  out[g * 128 + tid] = fmaxf(o, 0.f);
}

// ---------------- launch ----------------

extern "C" void kernel_launch(void* const* d_in, const int* in_sizes, int n_in,
                              void* d_out, int out_size, void* d_ws, size_t ws_size,
                              hipStream_t stream) {
  const float* x    = (const float*)d_in[0];
  const int*   src  = (const int*)d_in[1];
  const int*   dst  = (const int*)d_in[2];
  const int*   gid  = (const int*)d_in[3];
  const float* W1   = (const float*)d_in[4];
  const float* al1  = (const float*)d_in[5];
  const float* ar1  = (const float*)d_in[6];
  const float* b1   = (const float*)d_in[7];
  const float* W2   = (const float*)d_in[8];
  const float* al2  = (const float*)d_in[9];
  const float* ar2  = (const float*)d_in[10];
  const float* b2   = (const float*)d_in[11];
  const float* linW = (const float*)d_in[12];
  const float* linb = (const float*)d_in[13];
  float* out = (float*)d_out;

  char* ws = (char*)d_ws;
  size_t off = 0;
  auto alloc = [&](size_t bytes) -> void* {
    void* p = ws + off;
    off += (bytes + 255) & ~(size_t)255;
    return p;
  };
  float* f1      = (float*)alloc((size_t)NN * 384 * 4);
  float* h1      = (float*)alloc((size_t)NN * 384 * 4);
  float* f2      = (float*)alloc((size_t)NN * 128 * 4);
  float* h2      = (float*)alloc((size_t)NN * 128 * 4);
  float* el1     = (float*)alloc((size_t)NN * 3 * 4);
  float* er1     = (float*)alloc((size_t)NN * 3 * 4);
  float* el2     = (float*)alloc((size_t)NN * 4);
  float* er2     = (float*)alloc((size_t)NN * 4);
  int*   indeg   = (int*)alloc((size_t)NN * 4);
  int*   rowptr  = (int*)alloc((size_t)(NN + 1) * 4);
  int*   cursor  = (int*)alloc((size_t)NN * 4);
  int*   csr_src = (int*)alloc((size_t)NE * 4);
  float* gsums   = (float*)alloc((size_t)NG * 128 * 4);
  (void)ws_size;

  hipMemsetAsync(indeg, 0, (size_t)NN * 4, stream);
  hipMemsetAsync(cursor, 0, (size_t)NN * 4, stream);
  hipMemsetAsync(gsums, 0, (size_t)NG * 128 * 4, stream);

  hist_kernel<<<(NE + 255) / 256, 256, 0, stream>>>(dst, indeg, NE);
  exscan_kernel<<<1, 1024, 0, stream>>>(indeg, rowptr, NN);
  scatter_kernel<<<(NE + 255) / 256, 256, 0, stream>>>(src, dst, rowptr, cursor, csr_src, NE);

  gemm16_kernel<128, 384><<<dim3(1250, 3), 256, 0, stream>>>(x, W1, f1, NN);
  att_coef_kernel<<<(NN * 3 + 3) / 4, 256, 0, stream>>>(f1, al1, ar1, el1, er1, NN * 3, 3);
  aggregate_kernel<3, true><<<NN, 128, 0, stream>>>(f1, el1, er1, b1, rowptr, csr_src, h1);

  gemm16_kernel<384, 128><<<dim3(1250, 1), 256, 0, stream>>>(h1, W2, f2, NN);
  att_coef_kernel<<<(NN + 3) / 4, 256, 0, stream>>>(f2, al2, ar2, el2, er2, NN, 1);
  aggregate_kernel<1, false><<<NN, 128, 0, stream>>>(f2, el2, er2, b2, rowptr, csr_src, h2);

  pool_partial_kernel<<<NG * PSPLIT, 128, 0, stream>>>(h2, gid, gsums, NN);
  pool_final_kernel<<<NG, 128, 0, stream>>>(gsums, gid, linW, linb, out, NN);
}

// Round 3
// 340.143 us; speedup vs baseline: 2.0363x; 1.1581x over previous
//
#include <hip/hip_runtime.h>
#include <hip/hip_bf16.h>

#define NN 20000
#define NE 320000
#define NG 16
#define PSPLIT 32

// ---------------- CSR build ----------------

__global__ void hist_kernel(const int* __restrict__ dst, int* __restrict__ indeg, int E) {
  int e = blockIdx.x * 256 + threadIdx.x;
  if (e < E) atomicAdd(&indeg[dst[e]], 1);
}

__global__ void exscan_kernel(const int* __restrict__ in, int* __restrict__ outp, int n) {
  __shared__ int wsum[16];
  __shared__ int wexcl[16];
  __shared__ int tot_s;
  __shared__ int carry_s;
  int t = threadIdx.x;
  int lane = t & 63, wv = t >> 6;
  if (t == 0) carry_s = 0;
  __syncthreads();
  for (int base = 0; base < n; base += 1024) {
    int i = base + t;
    int v = (i < n) ? in[i] : 0;
    int x = v;
#pragma unroll
    for (int off = 1; off < 64; off <<= 1) {
      int y = __shfl_up(x, off);
      if (lane >= off) x += y;
    }
    if (lane == 63) wsum[wv] = x;
    __syncthreads();
    int carry = carry_s;
    if (t < 16) {
      int s = wsum[t];
      int xs = s;
#pragma unroll
      for (int off = 1; off < 16; off <<= 1) {
        int y = __shfl_up(xs, off);
        if (t >= off) xs += y;
      }
      wexcl[t] = xs - s;
      if (t == 15) tot_s = xs;
    }
    __syncthreads();
    if (i < n) outp[i] = carry + wexcl[wv] + (x - v);
    if (t == 0) carry_s = carry + tot_s;
  }
  if (t == 0) outp[n] = carry_s;
}

__global__ void scatter_kernel(const int* __restrict__ src, const int* __restrict__ dst,
                               const int* __restrict__ rowptr, int* __restrict__ cursor,
                               int* __restrict__ csr_src, int E) {
  int e = blockIdx.x * 256 + threadIdx.x;
  if (e < E) {
    int d = dst[e];
    int p = atomicAdd(&cursor[d], 1);
    csr_src[rowptr[d] + p] = src[e];
  }
}

// ---------------- GEMM: 64x128 tile, 256 threads, 4x8 per thread ----------------
// As[m][k] padded to 36 (2-way-free a-reads); Bs[k][n] 32x128, b-frag split
// into cols [tn*4..+3] and [64+tn*4..+3] so b128 reads are 2-way-free.

template <int K, int NFULL>
__launch_bounds__(256)
__global__ void gemm64_kernel(const float* __restrict__ A, const float* __restrict__ B,
                              float* __restrict__ C, int M) {
  __shared__ float As[64 * 36];
  __shared__ float Bs[32 * 128];
  int t = threadIdx.x;
  int m0 = blockIdx.x * 64;
  int n0 = blockIdx.y * 128;
  int tm = t >> 4, tn = t & 15;
  float acc[4][8];
#pragma unroll
  for (int i = 0; i < 4; i++)
#pragma unroll
    for (int j = 0; j < 8; j++) acc[i][j] = 0.f;

  for (int k0 = 0; k0 < K; k0 += 32) {
    // stage A: 64 rows x 32 k
#pragma unroll
    for (int i = 0; i < 2; i++) {
      int idx = t + i * 256;
      int r = idx >> 3, kq = (idx & 7) * 4;
      int gm = m0 + r;
      float4 v = make_float4(0.f, 0.f, 0.f, 0.f);
      if (gm < M) v = *(const float4*)&A[(size_t)gm * K + k0 + kq];
      *(float4*)&As[r * 36 + kq] = v;
    }
    // stage B: 32 k x 128 n
#pragma unroll
    for (int i = 0; i < 4; i++) {
      int idx = t + i * 256;
      int kk = idx >> 5, nq = (idx & 31) * 4;
      float4 v = *(const float4*)&B[(size_t)(k0 + kk) * NFULL + n0 + nq];
      *(float4*)&Bs[kk * 128 + nq] = v;
    }
    __syncthreads();
#pragma unroll 8
    for (int k = 0; k < 32; k++) {
      float af[4];
#pragma unroll
      for (int i = 0; i < 4; i++) af[i] = As[(tm * 4 + i) * 36 + k];
      float4 b0 = *(const float4*)&Bs[k * 128 + tn * 4];
      float4 b1 = *(const float4*)&Bs[k * 128 + 64 + tn * 4];
      float bf[8] = {b0.x, b0.y, b0.z, b0.w, b1.x, b1.y, b1.z, b1.w};
#pragma unroll
      for (int i = 0; i < 4; i++)
#pragma unroll
        for (int j = 0; j < 8; j++) acc[i][j] += af[i] * bf[j];
    }
    __syncthreads();
  }
#pragma unroll
  for (int i = 0; i < 4; i++) {
    int gm = m0 + tm * 4 + i;
    if (gm < M) {
      *(float4*)&C[(size_t)gm * NFULL + n0 + tn * 4] =
          make_float4(acc[i][0], acc[i][1], acc[i][2], acc[i][3]);
      *(float4*)&C[(size_t)gm * NFULL + n0 + 64 + tn * 4] =
          make_float4(acc[i][4], acc[i][5], acc[i][6], acc[i][7]);
    }
  }
}

// ---------------- attention coefficients ----------------

__global__ void att_coef_kernel(const float* __restrict__ f, const float* __restrict__ al,
                                const float* __restrict__ ar, float* __restrict__ el,
                                float* __restrict__ er, int NH, int H) {
  int w = (blockIdx.x * 256 + threadIdx.x) >> 6;
  int lane = threadIdx.x & 63;
  if (w >= NH) return;
  int h = w % H;
  const float* fr = f + (size_t)w * 128;
  float v0 = fr[lane], v1 = fr[64 + lane];
  float a0 = al[h * 128 + lane], a1 = al[h * 128 + 64 + lane];
  float r0 = ar[h * 128 + lane], r1 = ar[h * 128 + 64 + lane];
  float se = v0 * a0 + v1 * a1;
  float sr = v0 * r0 + v1 * r1;
  for (int off = 32; off; off >>= 1) {
    se += __shfl_down(se, off);
    sr += __shfl_down(sr, off);
  }
  if (lane == 0) { el[w] = se; er[w] = sr; }
}

// ---------------- aggregation, H=3 heads, float4 gather ----------------
// block 128; weight phase: thread-per-edge; gather: t<96, (h = t>>5, dquad = t&31)

__global__ void aggregate3_kernel(const float* __restrict__ f, const float* __restrict__ el,
                                  const float* __restrict__ er, const float* __restrict__ bias,
                                  const int* __restrict__ rowptr, const int* __restrict__ csr_src,
                                  float* __restrict__ out) {
  int n = blockIdx.x;
  int t = threadIdx.x;
  __shared__ float wbuf[3][128];
  __shared__ int sbuf[128];
  __shared__ float red[6];
  int rs = rowptr[n];
  int deg = rowptr[n + 1] - rs;
  float er0 = er[n * 3 + 0], er1 = er[n * 3 + 1], er2 = er[n * 3 + 2];
  float psum0 = 0.f, psum1 = 0.f, psum2 = 0.f;
  int h = t >> 5;
  int d = (t & 31) * 4;
  const float* fh = f + h * 128 + d;
  float4 acc = make_float4(0.f, 0.f, 0.f, 0.f);
  for (int base = 0; base < deg; base += 128) {
    int cnt = min(128, deg - base);
    if (t < cnt) {
      int s = csr_src[rs + base + t];
      sbuf[t] = s;
      float e0 = el[s * 3 + 0] + er0, e1 = el[s * 3 + 1] + er1, e2 = el[s * 3 + 2] + er2;
      e0 = e0 > 0.f ? e0 : 0.2f * e0;
      e1 = e1 > 0.f ? e1 : 0.2f * e1;
      e2 = e2 > 0.f ? e2 : 0.2f * e2;
      float w0 = __expf(e0), w1 = __expf(e1), w2 = __expf(e2);
      wbuf[0][t] = w0; wbuf[1][t] = w1; wbuf[2][t] = w2;
      psum0 += w0; psum1 += w1; psum2 += w2;
    }
    __syncthreads();
    if (t < 96) {
      int j = 0;
      for (; j + 4 <= cnt; j += 4) {
        int s0 = sbuf[j], s1 = sbuf[j + 1], s2 = sbuf[j + 2], s3 = sbuf[j + 3];
        float4 v0 = *(const float4*)(fh + (size_t)s0 * 384);
        float4 v1 = *(const float4*)(fh + (size_t)s1 * 384);
        float4 v2 = *(const float4*)(fh + (size_t)s2 * 384);
        float4 v3 = *(const float4*)(fh + (size_t)s3 * 384);
        float w0 = wbuf[h][j], w1 = wbuf[h][j + 1], w2 = wbuf[h][j + 2], w3 = wbuf[h][j + 3];
        acc.x += w0 * v0.x + w1 * v1.x + w2 * v2.x + w3 * v3.x;
        acc.y += w0 * v0.y + w1 * v1.y + w2 * v2.y + w3 * v3.y;
        acc.z += w0 * v0.z + w1 * v1.z + w2 * v2.z + w3 * v3.z;
        acc.w += w0 * v0.w + w1 * v1.w + w2 * v2.w + w3 * v3.w;
      }
      for (; j < cnt; j++) {
        int s = sbuf[j];
        float4 v = *(const float4*)(fh + (size_t)s * 384);
        float w = wbuf[h][j];
        acc.x += w * v.x; acc.y += w * v.y; acc.z += w * v.z; acc.w += w * v.w;
      }
    }
    __syncthreads();
  }
  for (int off = 32; off; off >>= 1) {
    psum0 += __shfl_down(psum0, off);
    psum1 += __shfl_down(psum1, off);
    psum2 += __shfl_down(psum2, off);
  }
  int wv = t >> 6, ln = t & 63;
  if (ln == 0) { red[wv * 3 + 0] = psum0; red[wv * 3 + 1] = psum1; red[wv * 3 + 2] = psum2; }
  __syncthreads();
  if (t < 96) {
    float dn = red[h] + red[3 + h];
    float inv = dn > 0.f ? 1.f / dn : 0.f;
    const float* bp = bias + h * 128 + d;
    float4 r;
    r.x = acc.x * inv + bp[0];
    r.y = acc.y * inv + bp[1];
    r.z = acc.z * inv + bp[2];
    r.w = acc.w * inv + bp[3];
    r.x = r.x > 0.f ? r.x : expm1f(r.x);
    r.y = r.y > 0.f ? r.y : expm1f(r.y);
    r.z = r.z > 0.f ? r.z : expm1f(r.z);
    r.w = r.w > 0.f ? r.w : expm1f(r.w);
    *(float4*)&out[(size_t)n * 384 + h * 128 + d] = r;
  }
}

// ---------------- aggregation, H=1, float4 gather, 4 edge-groups ----------------

__global__ void aggregate1_kernel(const float* __restrict__ f, const float* __restrict__ el,
                                  const float* __restrict__ er, const float* __restrict__ bias,
                                  const int* __restrict__ rowptr, const int* __restrict__ csr_src,
                                  float* __restrict__ out) {
  int n = blockIdx.x;
  int t = threadIdx.x;
  __shared__ float wbuf[128];
  __shared__ int sbuf[128];
  __shared__ float red[2];
  __shared__ float4 accbuf[4][32];
  int rs = rowptr[n];
  int deg = rowptr[n + 1] - rs;
  float ern = er[n];
  float psum = 0.f;
  int g = t >> 5;
  int d = (t & 31) * 4;
  const float* fd = f + d;
  float4 acc = make_float4(0.f, 0.f, 0.f, 0.f);
  for (int base = 0; base < deg; base += 128) {
    int cnt = min(128, deg - base);
    if (t < cnt) {
      int s = csr_src[rs + base + t];
      sbuf[t] = s;
      float e = el[s] + ern;
      e = e > 0.f ? e : 0.2f * e;
      float w = __expf(e);
      wbuf[t] = w;
      psum += w;
    }
    __syncthreads();
    int j = g;
    for (; j + 4 < cnt; j += 8) {
      int s0 = sbuf[j], s1 = sbuf[j + 4];
      float4 v0 = *(const float4*)(fd + (size_t)s0 * 128);
      float4 v1 = *(const float4*)(fd + (size_t)s1 * 128);
      float w0 = wbuf[j], w1 = wbuf[j + 4];
      acc.x += w0 * v0.x + w1 * v1.x;
      acc.y += w0 * v0.y + w1 * v1.y;
      acc.z += w0 * v0.z + w1 * v1.z;
      acc.w += w0 * v0.w + w1 * v1.w;
    }
    for (; j < cnt; j += 4) {
      int s = sbuf[j];
      float4 v = *(const float4*)(fd + (size_t)s * 128);
      float w = wbuf[j];
      acc.x += w * v.x; acc.y += w * v.y; acc.z += w * v.z; acc.w += w * v.w;
    }
    __syncthreads();
  }
  for (int off = 32; off; off >>= 1) psum += __shfl_down(psum, off);
  int wv = t >> 6, ln = t & 63;
  if (ln == 0) red[wv] = psum;
  accbuf[g][t & 31] = acc;
  __syncthreads();
  if (t < 32) {
    float4 a0 = accbuf[0][t], a1 = accbuf[1][t], a2 = accbuf[2][t], a3 = accbuf[3][t];
    float dn = red[0] + red[1];
    float inv = dn > 0.f ? 1.f / dn : 0.f;
    const float* bp = bias + t * 4;
    float4 r;
    r.x = (a0.x + a1.x + a2.x + a3.x) * inv + bp[0];
    r.y = (a0.y + a1.y + a2.y + a3.y) * inv + bp[1];
    r.z = (a0.z + a1.z + a2.z + a3.z) * inv + bp[2];
    r.w = (a0.w + a1.w + a2.w + a3.w) * inv + bp[3];
    *(float4*)&out[(size_t)n * 128 + t * 4] = r;
  }
}

// ---------------- mean-pool: 2-stage ----------------

__global__ void pool_partial_kernel(const float* __restrict__ h2, const int* __restrict__ gid,
                                    float* __restrict__ sums, int N) {
  int g = blockIdx.x / PSPLIT;
  int sp = blockIdx.x % PSPLIT;
  int tid = threadIdx.x;
  int lo0 = 0, hi0 = N;
  while (lo0 < hi0) { int m = (lo0 + hi0) >> 1; if (gid[m] < g) lo0 = m + 1; else hi0 = m; }
  int lo1 = lo0, hi1 = N;
  while (lo1 < hi1) { int m = (lo1 + hi1) >> 1; if (gid[m] < g + 1) lo1 = m + 1; else hi1 = m; }
  float a0 = 0.f, a1 = 0.f, a2 = 0.f, a3 = 0.f;
  int n = lo0 + sp;
  for (; n + 3 * PSPLIT < lo1; n += 4 * PSPLIT) {
    a0 += h2[(size_t)n * 128 + tid];
    a1 += h2[(size_t)(n + PSPLIT) * 128 + tid];
    a2 += h2[(size_t)(n + 2 * PSPLIT) * 128 + tid];
    a3 += h2[(size_t)(n + 3 * PSPLIT) * 128 + tid];
  }
  for (; n < lo1; n += PSPLIT) a0 += h2[(size_t)n * 128 + tid];
  float acc = (a0 + a1) + (a2 + a3);
  atomicAdd(&sums[g * 128 + tid], acc);
}

__global__ void pool_final_kernel(const float* __restrict__ sums, const int* __restrict__ gid,
                                  const float* __restrict__ linW, const float* __restrict__ linb,
                                  float* __restrict__ out, int N) {
  int g = blockIdx.x;
  int tid = threadIdx.x;
  int lo0 = 0, hi0 = N;
  while (lo0 < hi0) { int m = (lo0 + hi0) >> 1; if (gid[m] < g) lo0 = m + 1; else hi0 = m; }
  int lo1 = lo0, hi1 = N;
  while (lo1 < hi1) { int m = (lo1 + hi1) >> 1; if (gid[m] < g + 1) lo1 = m + 1; else hi1 = m; }
  int cnt = lo1 - lo0;
  float hg = sums[g * 128 + tid] / (float)(cnt > 0 ? cnt : 1);
  __shared__ float hgs[128];
  hgs[tid] = hg;
  __syncthreads();
  float o = linb[tid];
#pragma unroll 4
  for (int dd = 0; dd < 128; dd++) o += hgs[dd] * linW[dd * 128 + tid];
  out[g * 128 + tid] = fmaxf(o, 0.f);
}

// ---------------- launch ----------------

extern "C" void kernel_launch(void* const* d_in, const int* in_sizes, int n_in,
                              void* d_out, int out_size, void* d_ws, size_t ws_size,
                              hipStream_t stream) {
  const float* x    = (const float*)d_in[0];
  const int*   src  = (const int*)d_in[1];
  const int*   dst  = (const int*)d_in[2];
  const int*   gid  = (const int*)d_in[3];
  const float* W1   = (const float*)d_in[4];
  const float* al1  = (const float*)d_in[5];
  const float* ar1  = (const float*)d_in[6];
  const float* b1   = (const float*)d_in[7];
  const float* W2   = (const float*)d_in[8];
  const float* al2  = (const float*)d_in[9];
  const float* ar2  = (const float*)d_in[10];
  const float* b2   = (const float*)d_in[11];
  const float* linW = (const float*)d_in[12];
  const float* linb = (const float*)d_in[13];
  float* out = (float*)d_out;

  char* ws = (char*)d_ws;
  size_t off = 0;
  auto alloc = [&](size_t bytes) -> void* {
    void* p = ws + off;
    off += (bytes + 255) & ~(size_t)255;
    return p;
  };
  float* f1      = (float*)alloc((size_t)NN * 384 * 4);
  float* h1      = (float*)alloc((size_t)NN * 384 * 4);
  float* f2      = (float*)alloc((size_t)NN * 128 * 4);
  float* h2      = (float*)alloc((size_t)NN * 128 * 4);
  float* el1     = (float*)alloc((size_t)NN * 3 * 4);
  float* er1     = (float*)alloc((size_t)NN * 3 * 4);
  float* el2     = (float*)alloc((size_t)NN * 4);
  float* er2     = (float*)alloc((size_t)NN * 4);
  int*   indeg   = (int*)alloc((size_t)NN * 4);
  int*   rowptr  = (int*)alloc((size_t)(NN + 1) * 4);
  int*   cursor  = (int*)alloc((size_t)NN * 4);
  int*   csr_src = (int*)alloc((size_t)NE * 4);
  float* gsums   = (float*)alloc((size_t)NG * 128 * 4);
  (void)ws_size;

  hipMemsetAsync(indeg, 0, (size_t)NN * 4, stream);
  hipMemsetAsync(cursor, 0, (size_t)NN * 4, stream);
  hipMemsetAsync(gsums, 0, (size_t)NG * 128 * 4, stream);

  hist_kernel<<<(NE + 255) / 256, 256, 0, stream>>>(dst, indeg, NE);
  exscan_kernel<<<1, 1024, 0, stream>>>(indeg, rowptr, NN);
  scatter_kernel<<<(NE + 255) / 256, 256, 0, stream>>>(src, dst, rowptr, cursor, csr_src, NE);

  gemm64_kernel<128, 384><<<dim3(313, 3), 256, 0, stream>>>(x, W1, f1, NN);
  att_coef_kernel<<<(NN * 3 + 3) / 4, 256, 0, stream>>>(f1, al1, ar1, el1, er1, NN * 3, 3);
  aggregate3_kernel<<<NN, 128, 0, stream>>>(f1, el1, er1, b1, rowptr, csr_src, h1);

  gemm64_kernel<384, 128><<<dim3(313, 1), 256, 0, stream>>>(h1, W2, f2, NN);
  att_coef_kernel<<<(NN + 3) / 4, 256, 0, stream>>>(f2, al2, ar2, el2, er2, NN, 1);
  aggregate1_kernel<<<NN, 128, 0, stream>>>(f2, el2, er2, b2, rowptr, csr_src, h2);

  pool_partial_kernel<<<NG * PSPLIT, 128, 0, stream>>>(h2, gid, gsums, NN);
  pool_final_kernel<<<NG, 128, 0, stream>>>(gsums, gid, linW, linb, out, NN);
}

// Round 4
// 315.961 us; speedup vs baseline: 2.1921x; 1.0765x over previous
//
#include <hip/hip_runtime.h>
#include <hip/hip_bf16.h>

#define NN 20000
#define NE 320000
#define NG 16
#define PSPLIT 32

// ---------------- CSR build ----------------

__global__ void hist_kernel(const int* __restrict__ dst, int* __restrict__ indeg, int E) {
  int e = blockIdx.x * 256 + threadIdx.x;
  if (e < E) atomicAdd(&indeg[dst[e]], 1);
}

__global__ void exscan_kernel(const int* __restrict__ in, int* __restrict__ outp, int n) {
  __shared__ int wsum[16];
  __shared__ int wexcl[16];
  __shared__ int tot_s;
  __shared__ int carry_s;
  int t = threadIdx.x;
  int lane = t & 63, wv = t >> 6;
  if (t == 0) carry_s = 0;
  __syncthreads();
  for (int base = 0; base < n; base += 1024) {
    int i = base + t;
    int v = (i < n) ? in[i] : 0;
    int x = v;
#pragma unroll
    for (int off = 1; off < 64; off <<= 1) {
      int y = __shfl_up(x, off);
      if (lane >= off) x += y;
    }
    if (lane == 63) wsum[wv] = x;
    __syncthreads();
    int carry = carry_s;
    if (t < 16) {
      int s = wsum[t];
      int xs = s;
#pragma unroll
      for (int off = 1; off < 16; off <<= 1) {
        int y = __shfl_up(xs, off);
        if (t >= off) xs += y;
      }
      wexcl[t] = xs - s;
      if (t == 15) tot_s = xs;
    }
    __syncthreads();
    if (i < n) outp[i] = carry + wexcl[wv] + (x - v);
    if (t == 0) carry_s = carry + tot_s;
  }
  if (t == 0) outp[n] = carry_s;
}

__global__ void scatter_kernel(const int* __restrict__ src, const int* __restrict__ dst,
                               const int* __restrict__ rowptr, int* __restrict__ cursor,
                               int* __restrict__ csr_src, int E) {
  int e = blockIdx.x * 256 + threadIdx.x;
  if (e < E) {
    int d = dst[e];
    int p = atomicAdd(&cursor[d], 1);
    csr_src[rowptr[d] + p] = src[e];
  }
}

// ---------------- layer-1 attention vectors pushed through W1 ----------------
// wlr[j][k], j=0..2: W1_h @ al1_h (el), j=3..5: W1_h @ ar1_h (er)

__global__ void prep_wlr_kernel(const float* __restrict__ W1, const float* __restrict__ al1,
                                const float* __restrict__ ar1, float* __restrict__ wlr) {
  int t = blockIdx.x * 256 + threadIdx.x;  // 768 total
  if (t >= 768) return;
  int k = t & 127;
  int j = t >> 7;  // 0..5
  int h = j % 3;
  const float* av = (j < 3 ? al1 : ar1) + h * 128;
  const float* wrow = W1 + (size_t)k * 384 + h * 128;
  float s = 0.f;
#pragma unroll 4
  for (int d = 0; d < 128; d++) s += wrow[d] * av[d];
  wlr[j * 128 + k] = s;
}

// el1/er1 for all nodes: [N,128] x [128,6]; one wave per node
__global__ void elr_kernel(const float* __restrict__ x, const float* __restrict__ wlr,
                           float* __restrict__ el, float* __restrict__ er, int N) {
  __shared__ float wl_s[768];
  int t = threadIdx.x;
  for (int i = t; i < 768; i += 256) wl_s[i] = wlr[i];
  __syncthreads();
  int w = (blockIdx.x * 256 + t) >> 6;
  int lane = t & 63;
  if (w >= N) return;
  float v0 = x[(size_t)w * 128 + lane], v1 = x[(size_t)w * 128 + 64 + lane];
  float s[6];
#pragma unroll
  for (int j = 0; j < 6; j++) s[j] = v0 * wl_s[j * 128 + lane] + v1 * wl_s[j * 128 + 64 + lane];
#pragma unroll
  for (int off = 32; off; off >>= 1)
#pragma unroll
    for (int j = 0; j < 6; j++) s[j] += __shfl_down(s[j], off);
  if (lane == 0) {
    el[w * 3 + 0] = s[0]; el[w * 3 + 1] = s[1]; el[w * 3 + 2] = s[2];
    er[w * 3 + 0] = s[3]; er[w * 3 + 1] = s[4]; er[w * 3 + 2] = s[5];
  }
}

// ---------------- layer-1 aggregation in x-space ----------------
// aggx[n,h,:] = (sum_e w_e^h x[src_e,:]) / denom_h  -- gathers 512B/edge, used by 3 heads

__global__ void aggregate_x_kernel(const float* __restrict__ x, const float* __restrict__ el,
                                   const float* __restrict__ er, const int* __restrict__ rowptr,
                                   const int* __restrict__ csr_src, float* __restrict__ aggx) {
  int n = blockIdx.x;
  int t = threadIdx.x;  // 128
  __shared__ float wbuf[3][128];
  __shared__ int sbuf[128];
  __shared__ float red[6];
  __shared__ float4 accbuf[3][4][32];
  int rs = rowptr[n];
  int deg = rowptr[n + 1] - rs;
  float er0 = er[n * 3 + 0], er1 = er[n * 3 + 1], er2 = er[n * 3 + 2];
  float p0 = 0.f, p1 = 0.f, p2 = 0.f;
  int g = t >> 5, dq = t & 31;
  const float* xd = x + dq * 4;
  float4 a0 = make_float4(0, 0, 0, 0), a1 = a0, a2 = a0;
  for (int base = 0; base < deg; base += 128) {
    int cnt = min(128, deg - base);
    if (t < cnt) {
      int s = csr_src[rs + base + t];
      sbuf[t] = s;
      float e0 = el[s * 3 + 0] + er0, e1 = el[s * 3 + 1] + er1, e2 = el[s * 3 + 2] + er2;
      e0 = e0 > 0.f ? e0 : 0.2f * e0;
      e1 = e1 > 0.f ? e1 : 0.2f * e1;
      e2 = e2 > 0.f ? e2 : 0.2f * e2;
      float w0 = __expf(e0), w1 = __expf(e1), w2 = __expf(e2);
      wbuf[0][t] = w0; wbuf[1][t] = w1; wbuf[2][t] = w2;
      p0 += w0; p1 += w1; p2 += w2;
    }
    __syncthreads();
    int j = g;
    for (; j + 4 < cnt; j += 8) {
      int s0 = sbuf[j], s1 = sbuf[j + 4];
      float4 v0 = *(const float4*)(xd + (size_t)s0 * 128);
      float4 v1 = *(const float4*)(xd + (size_t)s1 * 128);
      float w00 = wbuf[0][j], w01 = wbuf[1][j], w02 = wbuf[2][j];
      float w10 = wbuf[0][j + 4], w11 = wbuf[1][j + 4], w12 = wbuf[2][j + 4];
      a0.x += w00 * v0.x + w10 * v1.x; a0.y += w00 * v0.y + w10 * v1.y;
      a0.z += w00 * v0.z + w10 * v1.z; a0.w += w00 * v0.w + w10 * v1.w;
      a1.x += w01 * v0.x + w11 * v1.x; a1.y += w01 * v0.y + w11 * v1.y;
      a1.z += w01 * v0.z + w11 * v1.z; a1.w += w01 * v0.w + w11 * v1.w;
      a2.x += w02 * v0.x + w12 * v1.x; a2.y += w02 * v0.y + w12 * v1.y;
      a2.z += w02 * v0.z + w12 * v1.z; a2.w += w02 * v0.w + w12 * v1.w;
    }
    for (; j < cnt; j += 4) {
      int s = sbuf[j];
      float4 v = *(const float4*)(xd + (size_t)s * 128);
      float w0 = wbuf[0][j], w1 = wbuf[1][j], w2 = wbuf[2][j];
      a0.x += w0 * v.x; a0.y += w0 * v.y; a0.z += w0 * v.z; a0.w += w0 * v.w;
      a1.x += w1 * v.x; a1.y += w1 * v.y; a1.z += w1 * v.z; a1.w += w1 * v.w;
      a2.x += w2 * v.x; a2.y += w2 * v.y; a2.z += w2 * v.z; a2.w += w2 * v.w;
    }
    __syncthreads();
  }
  for (int off = 32; off; off >>= 1) {
    p0 += __shfl_down(p0, off);
    p1 += __shfl_down(p1, off);
    p2 += __shfl_down(p2, off);
  }
  int wv = t >> 6, ln = t & 63;
  if (ln == 0) { red[wv * 3 + 0] = p0; red[wv * 3 + 1] = p1; red[wv * 3 + 2] = p2; }
  accbuf[0][g][dq] = a0;
  accbuf[1][g][dq] = a1;
  accbuf[2][g][dq] = a2;
  __syncthreads();
  if (t < 96) {
    int h = t >> 5, d = t & 31;
    float4 s0 = accbuf[h][0][d], s1 = accbuf[h][1][d], s2 = accbuf[h][2][d], s3 = accbuf[h][3][d];
    float dn = red[h] + red[3 + h];
    float inv = dn > 0.f ? 1.f / dn : 0.f;
    float4 r;
    r.x = (s0.x + s1.x + s2.x + s3.x) * inv;
    r.y = (s0.y + s1.y + s2.y + s3.y) * inv;
    r.z = (s0.z + s1.z + s2.z + s3.z) * inv;
    r.w = (s0.w + s1.w + s2.w + s3.w) * inv;
    *(float4*)&aggx[(size_t)n * 384 + h * 128 + d * 4] = r;
  }
}

// ---------------- GEMM: 64-row x 128-col tile, runtime strides, opt bias+ELU ----------------
// blockIdx.y selects head: pointers advance by the given per-head strides.

template <int K, bool BIAS_ELU>
__launch_bounds__(256)
__global__ void gemm64e_kernel(const float* __restrict__ A, int lda, int sA,
                               const float* __restrict__ B, int ldb, int sB,
                               float* __restrict__ C, int ldc, int sC,
                               const float* __restrict__ bias, int sBias, int M) {
  __shared__ float As[64 * 36];
  __shared__ float Bs[32 * 128];
  int hy = blockIdx.y;
  A += (size_t)hy * sA; B += (size_t)hy * sB; C += (size_t)hy * sC;
  if (BIAS_ELU) bias += (size_t)hy * sBias;
  int t = threadIdx.x;
  int m0 = blockIdx.x * 64;
  int tm = t >> 4, tn = t & 15;
  float acc[4][8];
#pragma unroll
  for (int i = 0; i < 4; i++)
#pragma unroll
    for (int j = 0; j < 8; j++) acc[i][j] = 0.f;

  for (int k0 = 0; k0 < K; k0 += 32) {
#pragma unroll
    for (int i = 0; i < 2; i++) {
      int idx = t + i * 256;
      int r = idx >> 3, kq = (idx & 7) * 4;
      int gm = m0 + r;
      float4 v = make_float4(0.f, 0.f, 0.f, 0.f);
      if (gm < M) v = *(const float4*)&A[(size_t)gm * lda + k0 + kq];
      *(float4*)&As[r * 36 + kq] = v;
    }
#pragma unroll
    for (int i = 0; i < 4; i++) {
      int idx = t + i * 256;
      int kk = idx >> 5, nq = (idx & 31) * 4;
      float4 v = *(const float4*)&B[(size_t)(k0 + kk) * ldb + nq];
      *(float4*)&Bs[kk * 128 + nq] = v;
    }
    __syncthreads();
#pragma unroll 8
    for (int k = 0; k < 32; k++) {
      float af[4];
#pragma unroll
      for (int i = 0; i < 4; i++) af[i] = As[(tm * 4 + i) * 36 + k];
      float4 b0 = *(const float4*)&Bs[k * 128 + tn * 4];
      float4 b1 = *(const float4*)&Bs[k * 128 + 64 + tn * 4];
      float bf[8] = {b0.x, b0.y, b0.z, b0.w, b1.x, b1.y, b1.z, b1.w};
#pragma unroll
      for (int i = 0; i < 4; i++)
#pragma unroll
        for (int j = 0; j < 8; j++) acc[i][j] += af[i] * bf[j];
    }
    __syncthreads();
  }
  float bv[8];
  if (BIAS_ELU) {
#pragma unroll
    for (int j = 0; j < 4; j++) { bv[j] = bias[tn * 4 + j]; bv[4 + j] = bias[64 + tn * 4 + j]; }
  }
#pragma unroll
  for (int i = 0; i < 4; i++) {
    int gm = m0 + tm * 4 + i;
    if (gm < M) {
      float r[8];
#pragma unroll
      for (int j = 0; j < 8; j++) {
        float v = acc[i][j];
        if (BIAS_ELU) {
          v += bv[j];
          v = v > 0.f ? v : expm1f(v);
        }
        r[j] = v;
      }
      *(float4*)&C[(size_t)gm * ldc + tn * 4] = make_float4(r[0], r[1], r[2], r[3]);
      *(float4*)&C[(size_t)gm * ldc + 64 + tn * 4] = make_float4(r[4], r[5], r[6], r[7]);
    }
  }
}

// ---------------- attention coefficients (layer 2, H=1, reads f2) ----------------

__global__ void att_coef_kernel(const float* __restrict__ f, const float* __restrict__ al,
                                const float* __restrict__ ar, float* __restrict__ el,
                                float* __restrict__ er, int NH) {
  int w = (blockIdx.x * 256 + threadIdx.x) >> 6;
  int lane = threadIdx.x & 63;
  if (w >= NH) return;
  const float* fr = f + (size_t)w * 128;
  float v0 = fr[lane], v1 = fr[64 + lane];
  float a0 = al[lane], a1 = al[64 + lane];
  float r0 = ar[lane], r1 = ar[64 + lane];
  float se = v0 * a0 + v1 * a1;
  float sr = v0 * r0 + v1 * r1;
  for (int off = 32; off; off >>= 1) {
    se += __shfl_down(se, off);
    sr += __shfl_down(sr, off);
  }
  if (lane == 0) { el[w] = se; er[w] = sr; }
}

// ---------------- layer-2 aggregation (H=1, gathers f2) ----------------

__global__ void aggregate1_kernel(const float* __restrict__ f, const float* __restrict__ el,
                                  const float* __restrict__ er, const float* __restrict__ bias,
                                  const int* __restrict__ rowptr, const int* __restrict__ csr_src,
                                  float* __restrict__ out) {
  int n = blockIdx.x;
  int t = threadIdx.x;
  __shared__ float wbuf[128];
  __shared__ int sbuf[128];
  __shared__ float red[2];
  __shared__ float4 accbuf[4][32];
  int rs = rowptr[n];
  int deg = rowptr[n + 1] - rs;
  float ern = er[n];
  float psum = 0.f;
  int g = t >> 5;
  int d = (t & 31) * 4;
  const float* fd = f + d;
  float4 acc = make_float4(0.f, 0.f, 0.f, 0.f);
  for (int base = 0; base < deg; base += 128) {
    int cnt = min(128, deg - base);
    if (t < cnt) {
      int s = csr_src[rs + base + t];
      sbuf[t] = s;
      float e = el[s] + ern;
      e = e > 0.f ? e : 0.2f * e;
      float w = __expf(e);
      wbuf[t] = w;
      psum += w;
    }
    __syncthreads();
    int j = g;
    for (; j + 4 < cnt; j += 8) {
      int s0 = sbuf[j], s1 = sbuf[j + 4];
      float4 v0 = *(const float4*)(fd + (size_t)s0 * 128);
      float4 v1 = *(const float4*)(fd + (size_t)s1 * 128);
      float w0 = wbuf[j], w1 = wbuf[j + 4];
      acc.x += w0 * v0.x + w1 * v1.x;
      acc.y += w0 * v0.y + w1 * v1.y;
      acc.z += w0 * v0.z + w1 * v1.z;
      acc.w += w0 * v0.w + w1 * v1.w;
    }
    for (; j < cnt; j += 4) {
      int s = sbuf[j];
      float4 v = *(const float4*)(fd + (size_t)s * 128);
      float w = wbuf[j];
      acc.x += w * v.x; acc.y += w * v.y; acc.z += w * v.z; acc.w += w * v.w;
    }
    __syncthreads();
  }
  for (int off = 32; off; off >>= 1) psum += __shfl_down(psum, off);
  int wv = t >> 6, ln = t & 63;
  if (ln == 0) red[wv] = psum;
  accbuf[g][t & 31] = acc;
  __syncthreads();
  if (t < 32) {
    float4 a0 = accbuf[0][t], a1 = accbuf[1][t], a2 = accbuf[2][t], a3 = accbuf[3][t];
    float dn = red[0] + red[1];
    float inv = dn > 0.f ? 1.f / dn : 0.f;
    const float* bp = bias + t * 4;
    float4 r;
    r.x = (a0.x + a1.x + a2.x + a3.x) * inv + bp[0];
    r.y = (a0.y + a1.y + a2.y + a3.y) * inv + bp[1];
    r.z = (a0.z + a1.z + a2.z + a3.z) * inv + bp[2];
    r.w = (a0.w + a1.w + a2.w + a3.w) * inv + bp[3];
    *(float4*)&out[(size_t)n * 128 + t * 4] = r;
  }
}

// ---------------- mean-pool: 2-stage ----------------

__global__ void pool_partial_kernel(const float* __restrict__ h2, const int* __restrict__ gid,
                                    float* __restrict__ sums, int N) {
  int g = blockIdx.x / PSPLIT;
  int sp = blockIdx.x % PSPLIT;
  int tid = threadIdx.x;
  int lo0 = 0, hi0 = N;
  while (lo0 < hi0) { int m = (lo0 + hi0) >> 1; if (gid[m] < g) lo0 = m + 1; else hi0 = m; }
  int lo1 = lo0, hi1 = N;
  while (lo1 < hi1) { int m = (lo1 + hi1) >> 1; if (gid[m] < g + 1) lo1 = m + 1; else hi1 = m; }
  float a0 = 0.f, a1 = 0.f, a2 = 0.f, a3 = 0.f;
  int n = lo0 + sp;
  for (; n + 3 * PSPLIT < lo1; n += 4 * PSPLIT) {
    a0 += h2[(size_t)n * 128 + tid];
    a1 += h2[(size_t)(n + PSPLIT) * 128 + tid];
    a2 += h2[(size_t)(n + 2 * PSPLIT) * 128 + tid];
    a3 += h2[(size_t)(n + 3 * PSPLIT) * 128 + tid];
  }
  for (; n < lo1; n += PSPLIT) a0 += h2[(size_t)n * 128 + tid];
  float acc = (a0 + a1) + (a2 + a3);
  atomicAdd(&sums[g * 128 + tid], acc);
}

__global__ void pool_final_kernel(const float* __restrict__ sums, const int* __restrict__ gid,
                                  const float* __restrict__ linW, const float* __restrict__ linb,
                                  float* __restrict__ out, int N) {
  int g = blockIdx.x;
  int tid = threadIdx.x;
  int lo0 = 0, hi0 = N;
  while (lo0 < hi0) { int m = (lo0 + hi0) >> 1; if (gid[m] < g) lo0 = m + 1; else hi0 = m; }
  int lo1 = lo0, hi1 = N;
  while (lo1 < hi1) { int m = (lo1 + hi1) >> 1; if (gid[m] < g + 1) lo1 = m + 1; else hi1 = m; }
  int cnt = lo1 - lo0;
  float hg = sums[g * 128 + tid] / (float)(cnt > 0 ? cnt : 1);
  __shared__ float hgs[128];
  hgs[tid] = hg;
  __syncthreads();
  float o = linb[tid];
#pragma unroll 4
  for (int dd = 0; dd < 128; dd++) o += hgs[dd] * linW[dd * 128 + tid];
  out[g * 128 + tid] = fmaxf(o, 0.f);
}

// ---------------- launch ----------------

extern "C" void kernel_launch(void* const* d_in, const int* in_sizes, int n_in,
                              void* d_out, int out_size, void* d_ws, size_t ws_size,
                              hipStream_t stream) {
  const float* x    = (const float*)d_in[0];
  const int*   src  = (const int*)d_in[1];
  const int*   dst  = (const int*)d_in[2];
  const int*   gid  = (const int*)d_in[3];
  const float* W1   = (const float*)d_in[4];
  const float* al1  = (const float*)d_in[5];
  const float* ar1  = (const float*)d_in[6];
  const float* b1   = (const float*)d_in[7];
  const float* W2   = (const float*)d_in[8];
  const float* al2  = (const float*)d_in[9];
  const float* ar2  = (const float*)d_in[10];
  const float* b2   = (const float*)d_in[11];
  const float* linW = (const float*)d_in[12];
  const float* linb = (const float*)d_in[13];
  float* out = (float*)d_out;

  char* ws = (char*)d_ws;
  size_t off = 0;
  auto alloc = [&](size_t bytes) -> void* {
    void* p = ws + off;
    off += (bytes + 255) & ~(size_t)255;
    return p;
  };
  float* aggx    = (float*)alloc((size_t)NN * 384 * 4);  // layer-1 x-space aggregate
  float* h1      = (float*)alloc((size_t)NN * 384 * 4);
  float* f2      = (float*)alloc((size_t)NN * 128 * 4);
  float* h2      = (float*)alloc((size_t)NN * 128 * 4);
  float* el1     = (float*)alloc((size_t)NN * 3 * 4);
  float* er1     = (float*)alloc((size_t)NN * 3 * 4);
  float* el2     = (float*)alloc((size_t)NN * 4);
  float* er2     = (float*)alloc((size_t)NN * 4);
  float* wlr     = (float*)alloc((size_t)768 * 4);
  int*   rowptr  = (int*)alloc((size_t)(NN + 1) * 4);
  int*   csr_src = (int*)alloc((size_t)NE * 4);
  // zero-initialized region (single memset): indeg, cursor, gsums
  int*   indeg   = (int*)alloc((size_t)NN * 4);
  int*   cursor  = (int*)alloc((size_t)NN * 4);
  float* gsums   = (float*)alloc((size_t)NG * 128 * 4);
  (void)ws_size;
  size_t zbytes = (char*)(gsums + NG * 128) - (char*)indeg;
  hipMemsetAsync(indeg, 0, zbytes, stream);

  // CSR build
  hist_kernel<<<(NE + 255) / 256, 256, 0, stream>>>(dst, indeg, NE);
  exscan_kernel<<<1, 1024, 0, stream>>>(indeg, rowptr, NN);
  scatter_kernel<<<(NE + 255) / 256, 256, 0, stream>>>(src, dst, rowptr, cursor, csr_src, NE);

  // Layer 1 (x-space): wlr -> el/er -> aggregate x -> per-head GEMM with bias+ELU
  prep_wlr_kernel<<<3, 256, 0, stream>>>(W1, al1, ar1, wlr);
  elr_kernel<<<(NN + 3) / 4, 256, 0, stream>>>(x, wlr, el1, er1, NN);
  aggregate_x_kernel<<<NN, 128, 0, stream>>>(x, el1, er1, rowptr, csr_src, aggx);
  gemm64e_kernel<128, true><<<dim3(313, 3), 256, 0, stream>>>(
      aggx, 384, 128, W1, 384, 128, h1, 384, 128, b1, 128, NN);

  // Layer 2: f2 = h1 @ W2 ; el2/er2 ; aggregate(+b2) -> h2
  gemm64e_kernel<384, false><<<dim3(313, 1), 256, 0, stream>>>(
      h1, 384, 0, W2, 128, 0, f2, 128, 0, nullptr, 0, NN);
  att_coef_kernel<<<(NN + 3) / 4, 256, 0, stream>>>(f2, al2, ar2, el2, er2, NN);
  aggregate1_kernel<<<NN, 128, 0, stream>>>(f2, el2, er2, b2, rowptr, csr_src, h2);

  // Mean-pool + linear head
  pool_partial_kernel<<<NG * PSPLIT, 128, 0, stream>>>(h2, gid, gsums, NN);
  pool_final_kernel<<<NG, 128, 0, stream>>>(gsums, gid, linW, linb, out, NN);
}

// Round 5
// 299.991 us; speedup vs baseline: 2.3088x; 1.0532x over previous
//
#include <hip/hip_runtime.h>
#include <hip/hip_bf16.h>

#define NN 20000
#define NE 320000
#define NG 16
#define PSPLIT 32

// ---------------- CSR build ----------------

__global__ void hist_kernel(const int* __restrict__ dst, int* __restrict__ indeg, int E) {
  int e = blockIdx.x * 256 + threadIdx.x;
  if (e < E) atomicAdd(&indeg[dst[e]], 1);
}

__global__ void exscan_kernel(const int* __restrict__ in, int* __restrict__ outp, int n) {
  __shared__ int wsum[16];
  __shared__ int wexcl[16];
  __shared__ int tot_s;
  __shared__ int carry_s;
  int t = threadIdx.x;
  int lane = t & 63, wv = t >> 6;
  if (t == 0) carry_s = 0;
  __syncthreads();
  for (int base = 0; base < n; base += 1024) {
    int i = base + t;
    int v = (i < n) ? in[i] : 0;
    int x = v;
#pragma unroll
    for (int off = 1; off < 64; off <<= 1) {
      int y = __shfl_up(x, off);
      if (lane >= off) x += y;
    }
    if (lane == 63) wsum[wv] = x;
    __syncthreads();
    int carry = carry_s;
    if (t < 16) {
      int s = wsum[t];
      int xs = s;
#pragma unroll
      for (int off = 1; off < 16; off <<= 1) {
        int y = __shfl_up(xs, off);
        if (t >= off) xs += y;
      }
      wexcl[t] = xs - s;
      if (t == 15) tot_s = xs;
    }
    __syncthreads();
    if (i < n) outp[i] = carry + wexcl[wv] + (x - v);
    if (t == 0) carry_s = carry + tot_s;
  }
  if (t == 0) outp[n] = carry_s;
}

__global__ void scatter_kernel(const int* __restrict__ src, const int* __restrict__ dst,
                               const int* __restrict__ rowptr, int* __restrict__ cursor,
                               int* __restrict__ csr_src, int E) {
  int e = blockIdx.x * 256 + threadIdx.x;
  if (e < E) {
    int d = dst[e];
    int p = atomicAdd(&cursor[d], 1);
    csr_src[rowptr[d] + p] = src[e];
  }
}

// ---------------- layer-1 attention vectors pushed through W1 ----------------

__global__ void prep_wlr_kernel(const float* __restrict__ W1, const float* __restrict__ al1,
                                const float* __restrict__ ar1, float* __restrict__ wlr) {
  int t = blockIdx.x * 256 + threadIdx.x;  // 768 total
  if (t >= 768) return;
  int k = t & 127;
  int j = t >> 7;  // 0..5
  int h = j % 3;
  const float* av = (j < 3 ? al1 : ar1) + h * 128;
  const float* wrow = W1 + (size_t)k * 384 + h * 128;
  float s = 0.f;
#pragma unroll 4
  for (int d = 0; d < 128; d++) s += wrow[d] * av[d];
  wlr[j * 128 + k] = s;
}

// el1/er1 for all nodes: [N,128] x [128,6]; one wave per node
__global__ void elr_kernel(const float* __restrict__ x, const float* __restrict__ wlr,
                           float* __restrict__ el, float* __restrict__ er, int N) {
  __shared__ float wl_s[768];
  int t = threadIdx.x;
  for (int i = t; i < 768; i += 256) wl_s[i] = wlr[i];
  __syncthreads();
  int w = (blockIdx.x * 256 + t) >> 6;
  int lane = t & 63;
  if (w >= N) return;
  float v0 = x[(size_t)w * 128 + lane], v1 = x[(size_t)w * 128 + 64 + lane];
  float s[6];
#pragma unroll
  for (int j = 0; j < 6; j++) s[j] = v0 * wl_s[j * 128 + lane] + v1 * wl_s[j * 128 + 64 + lane];
#pragma unroll
  for (int off = 32; off; off >>= 1)
#pragma unroll
    for (int j = 0; j < 6; j++) s[j] += __shfl_down(s[j], off);
  if (lane == 0) {
    el[w * 3 + 0] = s[0]; el[w * 3 + 1] = s[1]; el[w * 3 + 2] = s[2];
    er[w * 3 + 0] = s[3]; er[w * 3 + 1] = s[4]; er[w * 3 + 2] = s[5];
  }
}

// ---------------- layer-1 aggregation in x-space ----------------

__global__ void aggregate_x_kernel(const float* __restrict__ x, const float* __restrict__ el,
                                   const float* __restrict__ er, const int* __restrict__ rowptr,
                                   const int* __restrict__ csr_src, float* __restrict__ aggx) {
  int n = blockIdx.x;
  int t = threadIdx.x;  // 128
  __shared__ float wbuf[3][128];
  __shared__ int sbuf[128];
  __shared__ float red[6];
  __shared__ float4 accbuf[3][4][32];
  int rs = rowptr[n];
  int deg = rowptr[n + 1] - rs;
  float er0 = er[n * 3 + 0], er1 = er[n * 3 + 1], er2 = er[n * 3 + 2];
  float p0 = 0.f, p1 = 0.f, p2 = 0.f;
  int g = t >> 5, dq = t & 31;
  const float* xd = x + dq * 4;
  float4 a0 = make_float4(0, 0, 0, 0), a1 = a0, a2 = a0;
  for (int base = 0; base < deg; base += 128) {
    int cnt = min(128, deg - base);
    if (t < cnt) {
      int s = csr_src[rs + base + t];
      sbuf[t] = s;
      float e0 = el[s * 3 + 0] + er0, e1 = el[s * 3 + 1] + er1, e2 = el[s * 3 + 2] + er2;
      e0 = e0 > 0.f ? e0 : 0.2f * e0;
      e1 = e1 > 0.f ? e1 : 0.2f * e1;
      e2 = e2 > 0.f ? e2 : 0.2f * e2;
      float w0 = __expf(e0), w1 = __expf(e1), w2 = __expf(e2);
      wbuf[0][t] = w0; wbuf[1][t] = w1; wbuf[2][t] = w2;
      p0 += w0; p1 += w1; p2 += w2;
    }
    __syncthreads();
    int j = g;
    for (; j + 4 < cnt; j += 8) {
      int s0 = sbuf[j], s1 = sbuf[j + 4];
      float4 v0 = *(const float4*)(xd + (size_t)s0 * 128);
      float4 v1 = *(const float4*)(xd + (size_t)s1 * 128);
      float w00 = wbuf[0][j], w01 = wbuf[1][j], w02 = wbuf[2][j];
      float w10 = wbuf[0][j + 4], w11 = wbuf[1][j + 4], w12 = wbuf[2][j + 4];
      a0.x += w00 * v0.x + w10 * v1.x; a0.y += w00 * v0.y + w10 * v1.y;
      a0.z += w00 * v0.z + w10 * v1.z; a0.w += w00 * v0.w + w10 * v1.w;
      a1.x += w01 * v0.x + w11 * v1.x; a1.y += w01 * v0.y + w11 * v1.y;
      a1.z += w01 * v0.z + w11 * v1.z; a1.w += w01 * v0.w + w11 * v1.w;
      a2.x += w02 * v0.x + w12 * v1.x; a2.y += w02 * v0.y + w12 * v1.y;
      a2.z += w02 * v0.z + w12 * v1.z; a2.w += w02 * v0.w + w12 * v1.w;
    }
    for (; j < cnt; j += 4) {
      int s = sbuf[j];
      float4 v = *(const float4*)(xd + (size_t)s * 128);
      float w0 = wbuf[0][j], w1 = wbuf[1][j], w2 = wbuf[2][j];
      a0.x += w0 * v.x; a0.y += w0 * v.y; a0.z += w0 * v.z; a0.w += w0 * v.w;
      a1.x += w1 * v.x; a1.y += w1 * v.y; a1.z += w1 * v.z; a1.w += w1 * v.w;
      a2.x += w2 * v.x; a2.y += w2 * v.y; a2.z += w2 * v.z; a2.w += w2 * v.w;
    }
    __syncthreads();
  }
  for (int off = 32; off; off >>= 1) {
    p0 += __shfl_down(p0, off);
    p1 += __shfl_down(p1, off);
    p2 += __shfl_down(p2, off);
  }
  int wv = t >> 6, ln = t & 63;
  if (ln == 0) { red[wv * 3 + 0] = p0; red[wv * 3 + 1] = p1; red[wv * 3 + 2] = p2; }
  accbuf[0][g][dq] = a0;
  accbuf[1][g][dq] = a1;
  accbuf[2][g][dq] = a2;
  __syncthreads();
  if (t < 96) {
    int h = t >> 5, d = t & 31;
    float4 s0 = accbuf[h][0][d], s1 = accbuf[h][1][d], s2 = accbuf[h][2][d], s3 = accbuf[h][3][d];
    float dn = red[h] + red[3 + h];
    float inv = dn > 0.f ? 1.f / dn : 0.f;
    float4 r;
    r.x = (s0.x + s1.x + s2.x + s3.x) * inv;
    r.y = (s0.y + s1.y + s2.y + s3.y) * inv;
    r.z = (s0.z + s1.z + s2.z + s3.z) * inv;
    r.w = (s0.w + s1.w + s2.w + s3.w) * inv;
    *(float4*)&aggx[(size_t)n * 384 + h * 128 + d * 4] = r;
  }
}

// ---------------- GEMM: 32-row x 128-col tile, 625 blocks on M, opt bias+ELU ----------------
// M must be a multiple of 32 (20000 = 625*32) -> no bounds checks.
// blockIdx.y selects head via per-head strides.

template <int K, bool BIAS_ELU>
__launch_bounds__(256)
__global__ void gemm32e_kernel(const float* __restrict__ A, int lda, int sA,
                               const float* __restrict__ B, int ldb, int sB,
                               float* __restrict__ C, int ldc, int sC,
                               const float* __restrict__ bias, int sBias) {
  __shared__ float As[32 * 36];
  __shared__ float Bs[32 * 128];
  int hy = blockIdx.y;
  A += (size_t)hy * sA; B += (size_t)hy * sB; C += (size_t)hy * sC;
  if (BIAS_ELU) bias += (size_t)hy * sBias;
  int t = threadIdx.x;
  int m0 = blockIdx.x * 32;
  int tm = t >> 4, tn = t & 15;  // tm 0..15 -> 2 rows each; tn 0..15 -> 8 cols
  float acc[2][8];
#pragma unroll
  for (int i = 0; i < 2; i++)
#pragma unroll
    for (int j = 0; j < 8; j++) acc[i][j] = 0.f;

  for (int k0 = 0; k0 < K; k0 += 32) {
    {  // stage A: 32 rows x 32 k, one float4/thread
      int r = t >> 3, kq = (t & 7) * 4;
      float4 v = *(const float4*)&A[(size_t)(m0 + r) * lda + k0 + kq];
      *(float4*)&As[r * 36 + kq] = v;
    }
#pragma unroll
    for (int i = 0; i < 4; i++) {  // stage B: 32 k x 128 n
      int idx = t + i * 256;
      int kk = idx >> 5, nq = (idx & 31) * 4;
      float4 v = *(const float4*)&B[(size_t)(k0 + kk) * ldb + nq];
      *(float4*)&Bs[kk * 128 + nq] = v;
    }
    __syncthreads();
#pragma unroll
    for (int k = 0; k < 32; k++) {
      float a0 = As[(tm * 2 + 0) * 36 + k];
      float a1 = As[(tm * 2 + 1) * 36 + k];
      float4 b0 = *(const float4*)&Bs[k * 128 + tn * 4];
      float4 b1 = *(const float4*)&Bs[k * 128 + 64 + tn * 4];
      float bf[8] = {b0.x, b0.y, b0.z, b0.w, b1.x, b1.y, b1.z, b1.w};
#pragma unroll
      for (int j = 0; j < 8; j++) {
        acc[0][j] += a0 * bf[j];
        acc[1][j] += a1 * bf[j];
      }
    }
    __syncthreads();
  }
  float bv[8];
  if (BIAS_ELU) {
#pragma unroll
    for (int j = 0; j < 4; j++) { bv[j] = bias[tn * 4 + j]; bv[4 + j] = bias[64 + tn * 4 + j]; }
  }
#pragma unroll
  for (int i = 0; i < 2; i++) {
    int gm = m0 + tm * 2 + i;
    float r[8];
#pragma unroll
    for (int j = 0; j < 8; j++) {
      float v = acc[i][j];
      if (BIAS_ELU) {
        v += bv[j];
        v = v > 0.f ? v : expm1f(v);
      }
      r[j] = v;
    }
    *(float4*)&C[(size_t)gm * ldc + tn * 4] = make_float4(r[0], r[1], r[2], r[3]);
    *(float4*)&C[(size_t)gm * ldc + 64 + tn * 4] = make_float4(r[4], r[5], r[6], r[7]);
  }
}

// ---------------- attention coefficients (layer 2, H=1, reads f2) ----------------

__global__ void att_coef_kernel(const float* __restrict__ f, const float* __restrict__ al,
                                const float* __restrict__ ar, float* __restrict__ el,
                                float* __restrict__ er, int NH) {
  int w = (blockIdx.x * 256 + threadIdx.x) >> 6;
  int lane = threadIdx.x & 63;
  if (w >= NH) return;
  const float* fr = f + (size_t)w * 128;
  float v0 = fr[lane], v1 = fr[64 + lane];
  float a0 = al[lane], a1 = al[64 + lane];
  float r0 = ar[lane], r1 = ar[64 + lane];
  float se = v0 * a0 + v1 * a1;
  float sr = v0 * r0 + v1 * r1;
  for (int off = 32; off; off >>= 1) {
    se += __shfl_down(se, off);
    sr += __shfl_down(sr, off);
  }
  if (lane == 0) { el[w] = se; er[w] = sr; }
}

// ---------------- layer-2 aggregation (H=1, gathers f2) ----------------

__global__ void aggregate1_kernel(const float* __restrict__ f, const float* __restrict__ el,
                                  const float* __restrict__ er, const float* __restrict__ bias,
                                  const int* __restrict__ rowptr, const int* __restrict__ csr_src,
                                  float* __restrict__ out) {
  int n = blockIdx.x;
  int t = threadIdx.x;
  __shared__ float wbuf[128];
  __shared__ int sbuf[128];
  __shared__ float red[2];
  __shared__ float4 accbuf[4][32];
  int rs = rowptr[n];
  int deg = rowptr[n + 1] - rs;
  float ern = er[n];
  float psum = 0.f;
  int g = t >> 5;
  int d = (t & 31) * 4;
  const float* fd = f + d;
  float4 acc = make_float4(0.f, 0.f, 0.f, 0.f);
  for (int base = 0; base < deg; base += 128) {
    int cnt = min(128, deg - base);
    if (t < cnt) {
      int s = csr_src[rs + base + t];
      sbuf[t] = s;
      float e = el[s] + ern;
      e = e > 0.f ? e : 0.2f * e;
      float w = __expf(e);
      wbuf[t] = w;
      psum += w;
    }
    __syncthreads();
    int j = g;
    for (; j + 4 < cnt; j += 8) {
      int s0 = sbuf[j], s1 = sbuf[j + 4];
      float4 v0 = *(const float4*)(fd + (size_t)s0 * 128);
      float4 v1 = *(const float4*)(fd + (size_t)s1 * 128);
      float w0 = wbuf[j], w1 = wbuf[j + 4];
      acc.x += w0 * v0.x + w1 * v1.x;
      acc.y += w0 * v0.y + w1 * v1.y;
      acc.z += w0 * v0.z + w1 * v1.z;
      acc.w += w0 * v0.w + w1 * v1.w;
    }
    for (; j < cnt; j += 4) {
      int s = sbuf[j];
      float4 v = *(const float4*)(fd + (size_t)s * 128);
      float w = wbuf[j];
      acc.x += w * v.x; acc.y += w * v.y; acc.z += w * v.z; acc.w += w * v.w;
    }
    __syncthreads();
  }
  for (int off = 32; off; off >>= 1) psum += __shfl_down(psum, off);
  int wv = t >> 6, ln = t & 63;
  if (ln == 0) red[wv] = psum;
  accbuf[g][t & 31] = acc;
  __syncthreads();
  if (t < 32) {
    float4 a0 = accbuf[0][t], a1 = accbuf[1][t], a2 = accbuf[2][t], a3 = accbuf[3][t];
    float dn = red[0] + red[1];
    float inv = dn > 0.f ? 1.f / dn : 0.f;
    const float* bp = bias + t * 4;
    float4 r;
    r.x = (a0.x + a1.x + a2.x + a3.x) * inv + bp[0];
    r.y = (a0.y + a1.y + a2.y + a3.y) * inv + bp[1];
    r.z = (a0.z + a1.z + a2.z + a3.z) * inv + bp[2];
    r.w = (a0.w + a1.w + a2.w + a3.w) * inv + bp[3];
    *(float4*)&out[(size_t)n * 128 + t * 4] = r;
  }
}

// ---------------- mean-pool: 2-stage ----------------

__global__ void pool_partial_kernel(const float* __restrict__ h2, const int* __restrict__ gid,
                                    float* __restrict__ sums, int N) {
  int g = blockIdx.x / PSPLIT;
  int sp = blockIdx.x % PSPLIT;
  int tid = threadIdx.x;
  int lo0 = 0, hi0 = N;
  while (lo0 < hi0) { int m = (lo0 + hi0) >> 1; if (gid[m] < g) lo0 = m + 1; else hi0 = m; }
  int lo1 = lo0, hi1 = N;
  while (lo1 < hi1) { int m = (lo1 + hi1) >> 1; if (gid[m] < g + 1) lo1 = m + 1; else hi1 = m; }
  float a0 = 0.f, a1 = 0.f, a2 = 0.f, a3 = 0.f;
  int n = lo0 + sp;
  for (; n + 3 * PSPLIT < lo1; n += 4 * PSPLIT) {
    a0 += h2[(size_t)n * 128 + tid];
    a1 += h2[(size_t)(n + PSPLIT) * 128 + tid];
    a2 += h2[(size_t)(n + 2 * PSPLIT) * 128 + tid];
    a3 += h2[(size_t)(n + 3 * PSPLIT) * 128 + tid];
  }
  for (; n < lo1; n += PSPLIT) a0 += h2[(size_t)n * 128 + tid];
  float acc = (a0 + a1) + (a2 + a3);
  atomicAdd(&sums[g * 128 + tid], acc);
}

__global__ void pool_final_kernel(const float* __restrict__ sums, const int* __restrict__ gid,
                                  const float* __restrict__ linW, const float* __restrict__ linb,
                                  float* __restrict__ out, int N) {
  int g = blockIdx.x;
  int tid = threadIdx.x;
  int lo0 = 0, hi0 = N;
  while (lo0 < hi0) { int m = (lo0 + hi0) >> 1; if (gid[m] < g) lo0 = m + 1; else hi0 = m; }
  int lo1 = lo0, hi1 = N;
  while (lo1 < hi1) { int m = (lo1 + hi1) >> 1; if (gid[m] < g + 1) lo1 = m + 1; else hi1 = m; }
  int cnt = lo1 - lo0;
  float hg = sums[g * 128 + tid] / (float)(cnt > 0 ? cnt : 1);
  __shared__ float hgs[128];
  hgs[tid] = hg;
  __syncthreads();
  float o = linb[tid];
#pragma unroll 4
  for (int dd = 0; dd < 128; dd++) o += hgs[dd] * linW[dd * 128 + tid];
  out[g * 128 + tid] = fmaxf(o, 0.f);
}

// ---------------- launch ----------------

extern "C" void kernel_launch(void* const* d_in, const int* in_sizes, int n_in,
                              void* d_out, int out_size, void* d_ws, size_t ws_size,
                              hipStream_t stream) {
  const float* x    = (const float*)d_in[0];
  const int*   src  = (const int*)d_in[1];
  const int*   dst  = (const int*)d_in[2];
  const int*   gid  = (const int*)d_in[3];
  const float* W1   = (const float*)d_in[4];
  const float* al1  = (const float*)d_in[5];
  const float* ar1  = (const float*)d_in[6];
  const float* b1   = (const float*)d_in[7];
  const float* W2   = (const float*)d_in[8];
  const float* al2  = (const float*)d_in[9];
  const float* ar2  = (const float*)d_in[10];
  const float* b2   = (const float*)d_in[11];
  const float* linW = (const float*)d_in[12];
  const float* linb = (const float*)d_in[13];
  float* out = (float*)d_out;

  char* ws = (char*)d_ws;
  size_t off = 0;
  auto alloc = [&](size_t bytes) -> void* {
    void* p = ws + off;
    off += (bytes + 255) & ~(size_t)255;
    return p;
  };
  float* aggx    = (float*)alloc((size_t)NN * 384 * 4);
  float* h1      = (float*)alloc((size_t)NN * 384 * 4);
  float* f2      = (float*)alloc((size_t)NN * 128 * 4);
  float* h2      = (float*)alloc((size_t)NN * 128 * 4);
  float* el1     = (float*)alloc((size_t)NN * 3 * 4);
  float* er1     = (float*)alloc((size_t)NN * 3 * 4);
  float* el2     = (float*)alloc((size_t)NN * 4);
  float* er2     = (float*)alloc((size_t)NN * 4);
  float* wlr     = (float*)alloc((size_t)768 * 4);
  int*   rowptr  = (int*)alloc((size_t)(NN + 1) * 4);
  int*   csr_src = (int*)alloc((size_t)NE * 4);
  // zero-initialized region (single memset): indeg, cursor, gsums
  int*   indeg   = (int*)alloc((size_t)NN * 4);
  int*   cursor  = (int*)alloc((size_t)NN * 4);
  float* gsums   = (float*)alloc((size_t)NG * 128 * 4);
  (void)ws_size;
  size_t zbytes = (char*)(gsums + NG * 128) - (char*)indeg;
  hipMemsetAsync(indeg, 0, zbytes, stream);

  // CSR build
  hist_kernel<<<(NE + 255) / 256, 256, 0, stream>>>(dst, indeg, NE);
  exscan_kernel<<<1, 1024, 0, stream>>>(indeg, rowptr, NN);
  scatter_kernel<<<(NE + 255) / 256, 256, 0, stream>>>(src, dst, rowptr, cursor, csr_src, NE);

  // Layer 1 (x-space): wlr -> el/er -> aggregate x -> per-head GEMM with bias+ELU
  prep_wlr_kernel<<<3, 256, 0, stream>>>(W1, al1, ar1, wlr);
  elr_kernel<<<(NN + 3) / 4, 256, 0, stream>>>(x, wlr, el1, er1, NN);
  aggregate_x_kernel<<<NN, 128, 0, stream>>>(x, el1, er1, rowptr, csr_src, aggx);
  gemm32e_kernel<128, true><<<dim3(625, 3), 256, 0, stream>>>(
      aggx, 384, 128, W1, 384, 128, h1, 384, 128, b1, 128);

  // Layer 2: f2 = h1 @ W2 ; el2/er2 ; aggregate(+b2) -> h2
  gemm32e_kernel<384, false><<<dim3(625, 1), 256, 0, stream>>>(
      h1, 384, 0, W2, 128, 0, f2, 128, 0, nullptr, 0);
  att_coef_kernel<<<(NN + 3) / 4, 256, 0, stream>>>(f2, al2, ar2, el2, er2, NN);
  aggregate1_kernel<<<NN, 128, 0, stream>>>(f2, el2, er2, b2, rowptr, csr_src, h2);

  // Mean-pool + linear head
  pool_partial_kernel<<<NG * PSPLIT, 128, 0, stream>>>(h2, gid, gsums, NN);
  pool_final_kernel<<<NG, 128, 0, stream>>>(gsums, gid, linW, linb, out, NN);
}

// Round 6
// 290.456 us; speedup vs baseline: 2.3846x; 1.0328x over previous
//
#include <hip/hip_runtime.h>
#include <hip/hip_bf16.h>

#define NN 20000
#define NE 320000
#define NG 16
#define PSPLIT 32
#define NSCANB 79  // ceil(20000/256)

// ---------------- CSR build ----------------

__global__ void hist_kernel(const int* __restrict__ dst, int* __restrict__ indeg, int E) {
  int e = blockIdx.x * 256 + threadIdx.x;
  if (e < E) atomicAdd(&indeg[dst[e]], 1);
}

// hierarchical exclusive scan: per-block scan + block sums
__global__ void scan1_kernel(const int* __restrict__ in, int* __restrict__ outp,
                             int* __restrict__ bsum, int n) {
  int b = blockIdx.x, t = threadIdx.x;
  int i = b * 256 + t;
  int lane = t & 63, wv = t >> 6;
  __shared__ int ws[4];
  int v = (i < n) ? in[i] : 0;
  int x = v;
#pragma unroll
  for (int off = 1; off < 64; off <<= 1) {
    int y = __shfl_up(x, off);
    if (lane >= off) x += y;
  }
  if (lane == 63) ws[wv] = x;
  __syncthreads();
  int add = 0;
  for (int w2 = 0; w2 < wv; w2++) add += ws[w2];
  x += add;
  if (i < n) outp[i] = x - v;  // block-local exclusive
  if (t == 255) bsum[b] = x;   // block total
}

// scan block sums (nb <= 128), write offsets + grand total to rowptr[NN]
__global__ void scan2_kernel(const int* __restrict__ bsum, int* __restrict__ boff,
                             int* __restrict__ rp_end, int nb) {
  int t = threadIdx.x;  // 128
  int lane = t & 63, wv = t >> 6;
  __shared__ int ws[2];
  int v = (t < nb) ? bsum[t] : 0;
  int x = v;
#pragma unroll
  for (int off = 1; off < 64; off <<= 1) {
    int y = __shfl_up(x, off);
    if (lane >= off) x += y;
  }
  if (lane == 63) ws[wv] = x;
  __syncthreads();
  if (wv == 1) x += ws[0];
  if (t < nb) boff[t] = x - v;
  if (t == 127) *rp_end = x;
}

__global__ void scan3_kernel(int* __restrict__ outp, const int* __restrict__ boff, int n) {
  int i = blockIdx.x * 256 + threadIdx.x;
  if (i < n) outp[i] += boff[blockIdx.x];
}

__global__ void scatter_kernel(const int* __restrict__ src, const int* __restrict__ dst,
                               const int* __restrict__ rowptr, int* __restrict__ cursor,
                               int* __restrict__ csr_src, int E) {
  int e = blockIdx.x * 256 + threadIdx.x;
  if (e < E) {
    int d = dst[e];
    int p = atomicAdd(&cursor[d], 1);
    csr_src[rowptr[d] + p] = src[e];
  }
}

// ---------------- layer-1 attention vectors pushed through W1 ----------------

__global__ void prep_wlr_kernel(const float* __restrict__ W1, const float* __restrict__ al1,
                                const float* __restrict__ ar1, float* __restrict__ wlr) {
  int t = blockIdx.x * 256 + threadIdx.x;  // 768 total
  if (t >= 768) return;
  int k = t & 127;
  int j = t >> 7;  // 0..5
  int h = j % 3;
  const float* av = (j < 3 ? al1 : ar1) + h * 128;
  const float* wrow = W1 + (size_t)k * 384 + h * 128;
  float s = 0.f;
#pragma unroll 4
  for (int d = 0; d < 128; d++) s += wrow[d] * av[d];
  wlr[j * 128 + k] = s;
}

// el1/er1 for all nodes: one wave per node
__global__ void elr_kernel(const float* __restrict__ x, const float* __restrict__ wlr,
                           float* __restrict__ el, float* __restrict__ er, int N) {
  __shared__ float wl_s[768];
  int t = threadIdx.x;
  for (int i = t; i < 768; i += 256) wl_s[i] = wlr[i];
  __syncthreads();
  int w = (blockIdx.x * 256 + t) >> 6;
  int lane = t & 63;
  if (w >= N) return;
  float v0 = x[(size_t)w * 128 + lane], v1 = x[(size_t)w * 128 + 64 + lane];
  float s[6];
#pragma unroll
  for (int j = 0; j < 6; j++) s[j] = v0 * wl_s[j * 128 + lane] + v1 * wl_s[j * 128 + 64 + lane];
#pragma unroll
  for (int off = 32; off; off >>= 1)
#pragma unroll
    for (int j = 0; j < 6; j++) s[j] += __shfl_down(s[j], off);
  if (lane == 0) {
    el[w * 3 + 0] = s[0]; el[w * 3 + 1] = s[1]; el[w * 3 + 2] = s[2];
    er[w * 3 + 0] = s[3]; er[w * 3 + 1] = s[4]; er[w * 3 + 2] = s[5];
  }
}

// ---------------- layer-1 aggregation in x-space ----------------

__global__ void aggregate_x_kernel(const float* __restrict__ x, const float* __restrict__ el,
                                   const float* __restrict__ er, const int* __restrict__ rowptr,
                                   const int* __restrict__ csr_src, float* __restrict__ aggx) {
  int n = blockIdx.x;
  int t = threadIdx.x;  // 128
  __shared__ float wbuf[3][128];
  __shared__ int sbuf[128];
  __shared__ float red[6];
  __shared__ float4 accbuf[3][4][32];
  int rs = rowptr[n];
  int deg = rowptr[n + 1] - rs;
  float er0 = er[n * 3 + 0], er1 = er[n * 3 + 1], er2 = er[n * 3 + 2];
  float p0 = 0.f, p1 = 0.f, p2 = 0.f;
  int g = t >> 5, dq = t & 31;
  const float* xd = x + dq * 4;
  float4 a0 = make_float4(0, 0, 0, 0), a1 = a0, a2 = a0;
  for (int base = 0; base < deg; base += 128) {
    int cnt = min(128, deg - base);
    if (t < cnt) {
      int s = csr_src[rs + base + t];
      sbuf[t] = s;
      float e0 = el[s * 3 + 0] + er0, e1 = el[s * 3 + 1] + er1, e2 = el[s * 3 + 2] + er2;
      e0 = e0 > 0.f ? e0 : 0.2f * e0;
      e1 = e1 > 0.f ? e1 : 0.2f * e1;
      e2 = e2 > 0.f ? e2 : 0.2f * e2;
      float w0 = __expf(e0), w1 = __expf(e1), w2 = __expf(e2);
      wbuf[0][t] = w0; wbuf[1][t] = w1; wbuf[2][t] = w2;
      p0 += w0; p1 += w1; p2 += w2;
    }
    __syncthreads();
    int j = g;
    for (; j + 4 < cnt; j += 8) {
      int s0 = sbuf[j], s1 = sbuf[j + 4];
      float4 v0 = *(const float4*)(xd + (size_t)s0 * 128);
      float4 v1 = *(const float4*)(xd + (size_t)s1 * 128);
      float w00 = wbuf[0][j], w01 = wbuf[1][j], w02 = wbuf[2][j];
      float w10 = wbuf[0][j + 4], w11 = wbuf[1][j + 4], w12 = wbuf[2][j + 4];
      a0.x += w00 * v0.x + w10 * v1.x; a0.y += w00 * v0.y + w10 * v1.y;
      a0.z += w00 * v0.z + w10 * v1.z; a0.w += w00 * v0.w + w10 * v1.w;
      a1.x += w01 * v0.x + w11 * v1.x; a1.y += w01 * v0.y + w11 * v1.y;
      a1.z += w01 * v0.z + w11 * v1.z; a1.w += w01 * v0.w + w11 * v1.w;
      a2.x += w02 * v0.x + w12 * v1.x; a2.y += w02 * v0.y + w12 * v1.y;
      a2.z += w02 * v0.z + w12 * v1.z; a2.w += w02 * v0.w + w12 * v1.w;
    }
    for (; j < cnt; j += 4) {
      int s = sbuf[j];
      float4 v = *(const float4*)(xd + (size_t)s * 128);
      float w0 = wbuf[0][j], w1 = wbuf[1][j], w2 = wbuf[2][j];
      a0.x += w0 * v.x; a0.y += w0 * v.y; a0.z += w0 * v.z; a0.w += w0 * v.w;
      a1.x += w1 * v.x; a1.y += w1 * v.y; a1.z += w1 * v.z; a1.w += w1 * v.w;
      a2.x += w2 * v.x; a2.y += w2 * v.y; a2.z += w2 * v.z; a2.w += w2 * v.w;
    }
    __syncthreads();
  }
  for (int off = 32; off; off >>= 1) {
    p0 += __shfl_down(p0, off);
    p1 += __shfl_down(p1, off);
    p2 += __shfl_down(p2, off);
  }
  int wv = t >> 6, ln = t & 63;
  if (ln == 0) { red[wv * 3 + 0] = p0; red[wv * 3 + 1] = p1; red[wv * 3 + 2] = p2; }
  accbuf[0][g][dq] = a0;
  accbuf[1][g][dq] = a1;
  accbuf[2][g][dq] = a2;
  __syncthreads();
  if (t < 96) {
    int h = t >> 5, d = t & 31;
    float4 s0 = accbuf[h][0][d], s1 = accbuf[h][1][d], s2 = accbuf[h][2][d], s3 = accbuf[h][3][d];
    float dn = red[h] + red[3 + h];
    float inv = dn > 0.f ? 1.f / dn : 0.f;
    float4 r;
    r.x = (s0.x + s1.x + s2.x + s3.x) * inv;
    r.y = (s0.y + s1.y + s2.y + s3.y) * inv;
    r.z = (s0.z + s1.z + s2.z + s3.z) * inv;
    r.w = (s0.w + s1.w + s2.w + s3.w) * inv;
    *(float4*)&aggx[(size_t)n * 384 + h * 128 + d * 4] = r;
  }
}

// ---------------- GEMM: 32-row x 64-col tile, 128 threads, transposed-A LDS ----------------
// As[k][m] pad-40: A-fragment for 4 rows = one ds_read_b128 (conflict-free).
// M must be multiple of 32. blockIdx.y*64 = col tile; HEADS shifts A by (col0/128)*K.

template <int K, bool HEADS, bool BIAS_ELU>
__launch_bounds__(128)
__global__ void gemm3264_kernel(const float* __restrict__ A, int lda,
                                const float* __restrict__ B, int ldb,
                                float* __restrict__ C, int ldc,
                                const float* __restrict__ bias) {
  __shared__ float As[32 * 40];  // [k][m], pad 40
  __shared__ float Bs[32 * 64];  // [k][n]
  int t = threadIdx.x;
  int m0 = blockIdx.x * 32;
  int col0 = blockIdx.y * 64;
  if (HEADS) A += (size_t)(col0 >> 7) * 128;
  int tm = t >> 4, tn = t & 15;  // tm 0..7 (4 rows each), tn 0..15 (4 cols each)
  float acc[4][4];
#pragma unroll
  for (int i = 0; i < 4; i++)
#pragma unroll
    for (int j = 0; j < 4; j++) acc[i][j] = 0.f;

  for (int k0 = 0; k0 < K; k0 += 32) {
    // stage A 32x32, transposed into As[k][m]
#pragma unroll
    for (int i = 0; i < 2; i++) {
      int idx = t + i * 128;
      int r = idx >> 3, kq = (idx & 7) * 4;
      float4 v = *(const float4*)&A[(size_t)(m0 + r) * lda + k0 + kq];
      As[(kq + 0) * 40 + r] = v.x;
      As[(kq + 1) * 40 + r] = v.y;
      As[(kq + 2) * 40 + r] = v.z;
      As[(kq + 3) * 40 + r] = v.w;
    }
    // stage B 32x64
#pragma unroll
    for (int i = 0; i < 4; i++) {
      int idx = t + i * 128;
      int kk = idx >> 4, nq = (idx & 15) * 4;
      *(float4*)&Bs[kk * 64 + nq] = *(const float4*)&B[(size_t)(k0 + kk) * ldb + col0 + nq];
    }
    __syncthreads();
#pragma unroll
    for (int k = 0; k < 32; k++) {
      float4 a = *(const float4*)&As[k * 40 + tm * 4];
      float4 b = *(const float4*)&Bs[k * 64 + tn * 4];
      float af[4] = {a.x, a.y, a.z, a.w};
      float bf[4] = {b.x, b.y, b.z, b.w};
#pragma unroll
      for (int i = 0; i < 4; i++)
#pragma unroll
        for (int j = 0; j < 4; j++) acc[i][j] += af[i] * bf[j];
    }
    __syncthreads();
  }
  float bv[4];
  if (BIAS_ELU) {
#pragma unroll
    for (int j = 0; j < 4; j++) bv[j] = bias[col0 + tn * 4 + j];
  }
#pragma unroll
  for (int i = 0; i < 4; i++) {
    int gm = m0 + tm * 4 + i;
    float r[4];
#pragma unroll
    for (int j = 0; j < 4; j++) {
      float v = acc[i][j];
      if (BIAS_ELU) {
        v += bv[j];
        v = v > 0.f ? v : expm1f(v);
      }
      r[j] = v;
    }
    *(float4*)&C[(size_t)gm * ldc + col0 + tn * 4] = make_float4(r[0], r[1], r[2], r[3]);
  }
}

// ---------------- attention coefficients (layer 2, H=1, reads f2) ----------------

__global__ void att_coef_kernel(const float* __restrict__ f, const float* __restrict__ al,
                                const float* __restrict__ ar, float* __restrict__ el,
                                float* __restrict__ er, int NH) {
  int w = (blockIdx.x * 256 + threadIdx.x) >> 6;
  int lane = threadIdx.x & 63;
  if (w >= NH) return;
  const float* fr = f + (size_t)w * 128;
  float v0 = fr[lane], v1 = fr[64 + lane];
  float a0 = al[lane], a1 = al[64 + lane];
  float r0 = ar[lane], r1 = ar[64 + lane];
  float se = v0 * a0 + v1 * a1;
  float sr = v0 * r0 + v1 * r1;
  for (int off = 32; off; off >>= 1) {
    se += __shfl_down(se, off);
    sr += __shfl_down(sr, off);
  }
  if (lane == 0) { el[w] = se; er[w] = sr; }
}

// ---------------- layer-2 aggregation (H=1, gathers f2) ----------------

__global__ void aggregate1_kernel(const float* __restrict__ f, const float* __restrict__ el,
                                  const float* __restrict__ er, const float* __restrict__ bias,
                                  const int* __restrict__ rowptr, const int* __restrict__ csr_src,
                                  float* __restrict__ out) {
  int n = blockIdx.x;
  int t = threadIdx.x;
  __shared__ float wbuf[128];
  __shared__ int sbuf[128];
  __shared__ float red[2];
  __shared__ float4 accbuf[4][32];
  int rs = rowptr[n];
  int deg = rowptr[n + 1] - rs;
  float ern = er[n];
  float psum = 0.f;
  int g = t >> 5;
  int d = (t & 31) * 4;
  const float* fd = f + d;
  float4 acc = make_float4(0.f, 0.f, 0.f, 0.f);
  for (int base = 0; base < deg; base += 128) {
    int cnt = min(128, deg - base);
    if (t < cnt) {
      int s = csr_src[rs + base + t];
      sbuf[t] = s;
      float e = el[s] + ern;
      e = e > 0.f ? e : 0.2f * e;
      float w = __expf(e);
      wbuf[t] = w;
      psum += w;
    }
    __syncthreads();
    int j = g;
    for (; j + 4 < cnt; j += 8) {
      int s0 = sbuf[j], s1 = sbuf[j + 4];
      float4 v0 = *(const float4*)(fd + (size_t)s0 * 128);
      float4 v1 = *(const float4*)(fd + (size_t)s1 * 128);
      float w0 = wbuf[j], w1 = wbuf[j + 4];
      acc.x += w0 * v0.x + w1 * v1.x;
      acc.y += w0 * v0.y + w1 * v1.y;
      acc.z += w0 * v0.z + w1 * v1.z;
      acc.w += w0 * v0.w + w1 * v1.w;
    }
    for (; j < cnt; j += 4) {
      int s = sbuf[j];
      float4 v = *(const float4*)(fd + (size_t)s * 128);
      float w = wbuf[j];
      acc.x += w * v.x; acc.y += w * v.y; acc.z += w * v.z; acc.w += w * v.w;
    }
    __syncthreads();
  }
  for (int off = 32; off; off >>= 1) psum += __shfl_down(psum, off);
  int wv = t >> 6, ln = t & 63;
  if (ln == 0) red[wv] = psum;
  accbuf[g][t & 31] = acc;
  __syncthreads();
  if (t < 32) {
    float4 a0 = accbuf[0][t], a1 = accbuf[1][t], a2 = accbuf[2][t], a3 = accbuf[3][t];
    float dn = red[0] + red[1];
    float inv = dn > 0.f ? 1.f / dn : 0.f;
    const float* bp = bias + t * 4;
    float4 r;
    r.x = (a0.x + a1.x + a2.x + a3.x) * inv + bp[0];
    r.y = (a0.y + a1.y + a2.y + a3.y) * inv + bp[1];
    r.z = (a0.z + a1.z + a2.z + a3.z) * inv + bp[2];
    r.w = (a0.w + a1.w + a2.w + a3.w) * inv + bp[3];
    *(float4*)&out[(size_t)n * 128 + t * 4] = r;
  }
}

// ---------------- mean-pool: 2-stage ----------------

__global__ void pool_partial_kernel(const float* __restrict__ h2, const int* __restrict__ gid,
                                    float* __restrict__ sums, int N) {
  int g = blockIdx.x / PSPLIT;
  int sp = blockIdx.x % PSPLIT;
  int tid = threadIdx.x;
  int lo0 = 0, hi0 = N;
  while (lo0 < hi0) { int m = (lo0 + hi0) >> 1; if (gid[m] < g) lo0 = m + 1; else hi0 = m; }
  int lo1 = lo0, hi1 = N;
  while (lo1 < hi1) { int m = (lo1 + hi1) >> 1; if (gid[m] < g + 1) lo1 = m + 1; else hi1 = m; }
  float a0 = 0.f, a1 = 0.f, a2 = 0.f, a3 = 0.f;
  int n = lo0 + sp;
  for (; n + 3 * PSPLIT < lo1; n += 4 * PSPLIT) {
    a0 += h2[(size_t)n * 128 + tid];
    a1 += h2[(size_t)(n + PSPLIT) * 128 + tid];
    a2 += h2[(size_t)(n + 2 * PSPLIT) * 128 + tid];
    a3 += h2[(size_t)(n + 3 * PSPLIT) * 128 + tid];
  }
  for (; n < lo1; n += PSPLIT) a0 += h2[(size_t)n * 128 + tid];
  float acc = (a0 + a1) + (a2 + a3);
  atomicAdd(&sums[g * 128 + tid], acc);
}

__global__ void pool_final_kernel(const float* __restrict__ sums, const int* __restrict__ gid,
                                  const float* __restrict__ linW, const float* __restrict__ linb,
                                  float* __restrict__ out, int N) {
  int g = blockIdx.x;
  int tid = threadIdx.x;
  int lo0 = 0, hi0 = N;
  while (lo0 < hi0) { int m = (lo0 + hi0) >> 1; if (gid[m] < g) lo0 = m + 1; else hi0 = m; }
  int lo1 = lo0, hi1 = N;
  while (lo1 < hi1) { int m = (lo1 + hi1) >> 1; if (gid[m] < g + 1) lo1 = m + 1; else hi1 = m; }
  int cnt = lo1 - lo0;
  float hg = sums[g * 128 + tid] / (float)(cnt > 0 ? cnt : 1);
  __shared__ float hgs[128];
  hgs[tid] = hg;
  __syncthreads();
  float o = linb[tid];
#pragma unroll 4
  for (int dd = 0; dd < 128; dd++) o += hgs[dd] * linW[dd * 128 + tid];
  out[g * 128 + tid] = fmaxf(o, 0.f);
}

// ---------------- launch ----------------

extern "C" void kernel_launch(void* const* d_in, const int* in_sizes, int n_in,
                              void* d_out, int out_size, void* d_ws, size_t ws_size,
                              hipStream_t stream) {
  const float* x    = (const float*)d_in[0];
  const int*   src  = (const int*)d_in[1];
  const int*   dst  = (const int*)d_in[2];
  const int*   gid  = (const int*)d_in[3];
  const float* W1   = (const float*)d_in[4];
  const float* al1  = (const float*)d_in[5];
  const float* ar1  = (const float*)d_in[6];
  const float* b1   = (const float*)d_in[7];
  const float* W2   = (const float*)d_in[8];
  const float* al2  = (const float*)d_in[9];
  const float* ar2  = (const float*)d_in[10];
  const float* b2   = (const float*)d_in[11];
  const float* linW = (const float*)d_in[12];
  const float* linb = (const float*)d_in[13];
  float* out = (float*)d_out;

  char* ws = (char*)d_ws;
  size_t off = 0;
  auto alloc = [&](size_t bytes) -> void* {
    void* p = ws + off;
    off += (bytes + 255) & ~(size_t)255;
    return p;
  };
  float* aggx    = (float*)alloc((size_t)NN * 384 * 4);
  float* h1      = (float*)alloc((size_t)NN * 384 * 4);
  float* f2      = (float*)alloc((size_t)NN * 128 * 4);
  float* h2      = (float*)alloc((size_t)NN * 128 * 4);
  float* el1     = (float*)alloc((size_t)NN * 3 * 4);
  float* er1     = (float*)alloc((size_t)NN * 3 * 4);
  float* el2     = (float*)alloc((size_t)NN * 4);
  float* er2     = (float*)alloc((size_t)NN * 4);
  float* wlr     = (float*)alloc((size_t)768 * 4);
  int*   rowptr  = (int*)alloc((size_t)(NN + 1) * 4);
  int*   csr_src = (int*)alloc((size_t)NE * 4);
  int*   bsum    = (int*)alloc((size_t)NSCANB * 4);
  int*   boff    = (int*)alloc((size_t)NSCANB * 4);
  // zero-initialized region (single memset): indeg, cursor, gsums
  int*   indeg   = (int*)alloc((size_t)NN * 4);
  int*   cursor  = (int*)alloc((size_t)NN * 4);
  float* gsums   = (float*)alloc((size_t)NG * 128 * 4);
  (void)ws_size;
  size_t zbytes = (char*)(gsums + NG * 128) - (char*)indeg;
  hipMemsetAsync(indeg, 0, zbytes, stream);

  // CSR build (hierarchical scan)
  hist_kernel<<<(NE + 255) / 256, 256, 0, stream>>>(dst, indeg, NE);
  scan1_kernel<<<NSCANB, 256, 0, stream>>>(indeg, rowptr, bsum, NN);
  scan2_kernel<<<1, 128, 0, stream>>>(bsum, boff, rowptr + NN, NSCANB);
  scan3_kernel<<<NSCANB, 256, 0, stream>>>(rowptr, boff, NN);
  scatter_kernel<<<(NE + 255) / 256, 256, 0, stream>>>(src, dst, rowptr, cursor, csr_src, NE);

  // Layer 1 (x-space): wlr -> el/er -> aggregate x -> per-head GEMM with bias+ELU
  prep_wlr_kernel<<<3, 256, 0, stream>>>(W1, al1, ar1, wlr);
  elr_kernel<<<(NN + 3) / 4, 256, 0, stream>>>(x, wlr, el1, er1, NN);
  aggregate_x_kernel<<<NN, 128, 0, stream>>>(x, el1, er1, rowptr, csr_src, aggx);
  gemm3264_kernel<128, true, true><<<dim3(625, 6), 128, 0, stream>>>(
      aggx, 384, W1, 384, h1, 384, b1);

  // Layer 2: f2 = h1 @ W2 ; el2/er2 ; aggregate(+b2) -> h2
  gemm3264_kernel<384, false, false><<<dim3(625, 2), 128, 0, stream>>>(
      h1, 384, W2, 128, f2, 128, nullptr);
  att_coef_kernel<<<(NN + 3) / 4, 256, 0, stream>>>(f2, al2, ar2, el2, er2, NN);
  aggregate1_kernel<<<NN, 128, 0, stream>>>(f2, el2, er2, b2, rowptr, csr_src, h2);

  // Mean-pool + linear head
  pool_partial_kernel<<<NG * PSPLIT, 128, 0, stream>>>(h2, gid, gsums, NN);
  pool_final_kernel<<<NG, 128, 0, stream>>>(gsums, gid, linW, linb, out, NN);
}